// Round 1
// baseline (3092.355 us; speedup 1.0000x reference)
//
#include <hip/hip_runtime.h>

#define NN 50000
#define NE 800000
#define BE 64
#define PAD 8
#define TE (BE + PAD)

// ---------------------------------------------------------------------------
// Edge kernel: per 64-edge tile, compute
//   h = relu([x[src] | pe] @ W1 + b1);  msg = h @ W2 + b2;  atomicAdd(agg[dst], msg)
// Thread layout: 256 threads = 16 (tx: 8 cols each) x 16 (ty: 4 edges each).
// ---------------------------------------------------------------------------
__global__ __launch_bounds__(256)
void edge_msg_kernel(const float* __restrict__ x,
                     const float* __restrict__ pe,
                     const float* __restrict__ W1,
                     const float* __restrict__ b1,
                     const float* __restrict__ W2,
                     const float* __restrict__ b2,
                     const int*   __restrict__ ei,   // [2][NE], int32
                     float*       __restrict__ agg)  // [NN][128] (pre-zeroed)
{
    __shared__ float As[16][TE];    // A^T k-tile: As[kk][edge]
    __shared__ float Wt[16][128];   // W k-tile
    __shared__ float Ht[128][TE];   // h^T full: Ht[j][edge]

    const int t  = threadIdx.x;
    const int tx = t & 15;          // output-col group: j = tx*8 .. +7
    const int ty = t >> 4;          // edge group: e = ty*4 .. +3
    const int e0 = blockIdx.x * BE;

    // loader mapping: each thread loads one float4 of A per k-tile
    const int le = t >> 2;          // edge 0..63
    const int lq = (t & 3) * 4;     // k offset within tile
    const int src = ei[e0 + le];
    const int wrow = t >> 4;        // W-tile row 0..15
    const int wcol = (t & 15) * 8;  // W-tile col

    float acc[4][8];
#pragma unroll
    for (int i = 0; i < 4; ++i)
#pragma unroll
        for (int j = 0; j < 8; ++j) acc[i][j] = 0.f;

    // ---------------- layer 1: K = 192 ----------------
    for (int k0 = 0; k0 < 192; k0 += 16) {
        const int k = k0 + lq;
        float4 av;
        if (k < 128) av = *reinterpret_cast<const float4*>(&x[(long long)src * 128 + k]);
        else         av = *reinterpret_cast<const float4*>(&pe[(long long)(e0 + le) * 64 + (k - 128)]);
        const float* wp = &W1[(k0 + wrow) * 128 + wcol];
        const float4 w0 = *reinterpret_cast<const float4*>(wp);
        const float4 w1 = *reinterpret_cast<const float4*>(wp + 4);

        __syncthreads();   // previous tile fully consumed
        As[lq + 0][le] = av.x;
        As[lq + 1][le] = av.y;
        As[lq + 2][le] = av.z;
        As[lq + 3][le] = av.w;
        *reinterpret_cast<float4*>(&Wt[wrow][wcol])     = w0;
        *reinterpret_cast<float4*>(&Wt[wrow][wcol + 4]) = w1;
        __syncthreads();

#pragma unroll
        for (int kk = 0; kk < 16; ++kk) {
            const float4 a  = *reinterpret_cast<const float4*>(&As[kk][ty * 4]);
            const float4 wl = *reinterpret_cast<const float4*>(&Wt[kk][tx * 8]);
            const float4 wh = *reinterpret_cast<const float4*>(&Wt[kk][tx * 8 + 4]);
            const float a4[4] = {a.x, a.y, a.z, a.w};
            const float w8[8] = {wl.x, wl.y, wl.z, wl.w, wh.x, wh.y, wh.z, wh.w};
#pragma unroll
            for (int i = 0; i < 4; ++i)
#pragma unroll
                for (int j = 0; j < 8; ++j)
                    acc[i][j] = fmaf(a4[i], w8[j], acc[i][j]);
        }
    }

    // bias + relu -> Ht (h transposed), reset acc for layer 2
#pragma unroll
    for (int j = 0; j < 8; ++j) {
        const float bj = b1[tx * 8 + j];
#pragma unroll
        for (int i = 0; i < 4; ++i) {
            const float v = acc[i][j] + bj;
            Ht[tx * 8 + j][ty * 4 + i] = v > 0.f ? v : 0.f;
            acc[i][j] = 0.f;
        }
    }

    // ---------------- layer 2: K = 128 ----------------
    for (int k0 = 0; k0 < 128; k0 += 16) {
        const float* wp = &W2[(k0 + wrow) * 128 + wcol];
        const float4 w0 = *reinterpret_cast<const float4*>(wp);
        const float4 w1 = *reinterpret_cast<const float4*>(wp + 4);
        __syncthreads();   // Ht writes visible; previous Wt consumed
        *reinterpret_cast<float4*>(&Wt[wrow][wcol])     = w0;
        *reinterpret_cast<float4*>(&Wt[wrow][wcol + 4]) = w1;
        __syncthreads();

#pragma unroll
        for (int kk = 0; kk < 16; ++kk) {
            const float4 a  = *reinterpret_cast<const float4*>(&Ht[k0 + kk][ty * 4]);
            const float4 wl = *reinterpret_cast<const float4*>(&Wt[kk][tx * 8]);
            const float4 wh = *reinterpret_cast<const float4*>(&Wt[kk][tx * 8 + 4]);
            const float a4[4] = {a.x, a.y, a.z, a.w};
            const float w8[8] = {wl.x, wl.y, wl.z, wl.w, wh.x, wh.y, wh.z, wh.w};
#pragma unroll
            for (int i = 0; i < 4; ++i)
#pragma unroll
                for (int j = 0; j < 8; ++j)
                    acc[i][j] = fmaf(a4[i], w8[j], acc[i][j]);
        }
    }

    // bias + scatter-add
#pragma unroll
    for (int i = 0; i < 4; ++i) {
        const int dst = ei[NE + e0 + ty * 4 + i];
        float* ap = &agg[(long long)dst * 128 + tx * 8];
#pragma unroll
        for (int j = 0; j < 8; ++j)
            atomicAdd(ap + j, acc[i][j] + b2[tx * 8 + j]);
    }
}

// ---------------------------------------------------------------------------
// Node kernel: out = relu([x | agg] @ U1 + c1) @ U2 + c2
// agg lives in `out` (d_out); each block reads only its own 64 rows before
// overwriting them, so in-place is safe.
// ---------------------------------------------------------------------------
__global__ __launch_bounds__(256)
void node_upd_kernel(const float* __restrict__ x,
                     const float* __restrict__ U1,
                     const float* __restrict__ c1,
                     const float* __restrict__ U2,
                     const float* __restrict__ c2,
                     float*       __restrict__ out)  // in: agg, out: result
{
    __shared__ float As[16][TE];
    __shared__ float Wt[16][128];
    __shared__ float Ht[128][TE];

    const int t  = threadIdx.x;
    const int tx = t & 15;
    const int ty = t >> 4;
    const int n0 = blockIdx.x * BE;

    const int le = t >> 2;
    const int lq = (t & 3) * 4;
    const int node = n0 + le;
    const bool lvalid = node < NN;
    const int wrow = t >> 4;
    const int wcol = (t & 15) * 8;

    float acc[4][8];
#pragma unroll
    for (int i = 0; i < 4; ++i)
#pragma unroll
        for (int j = 0; j < 8; ++j) acc[i][j] = 0.f;

    // ---------------- layer 1: K = 256 ----------------
    for (int k0 = 0; k0 < 256; k0 += 16) {
        const int k = k0 + lq;
        float4 av = make_float4(0.f, 0.f, 0.f, 0.f);
        if (lvalid) {
            if (k < 128) av = *reinterpret_cast<const float4*>(&x[(long long)node * 128 + k]);
            else         av = *reinterpret_cast<const float4*>(&out[(long long)node * 128 + (k - 128)]);
        }
        const float* wp = &U1[(k0 + wrow) * 128 + wcol];
        const float4 w0 = *reinterpret_cast<const float4*>(wp);
        const float4 w1 = *reinterpret_cast<const float4*>(wp + 4);

        __syncthreads();
        As[lq + 0][le] = av.x;
        As[lq + 1][le] = av.y;
        As[lq + 2][le] = av.z;
        As[lq + 3][le] = av.w;
        *reinterpret_cast<float4*>(&Wt[wrow][wcol])     = w0;
        *reinterpret_cast<float4*>(&Wt[wrow][wcol + 4]) = w1;
        __syncthreads();

#pragma unroll
        for (int kk = 0; kk < 16; ++kk) {
            const float4 a  = *reinterpret_cast<const float4*>(&As[kk][ty * 4]);
            const float4 wl = *reinterpret_cast<const float4*>(&Wt[kk][tx * 8]);
            const float4 wh = *reinterpret_cast<const float4*>(&Wt[kk][tx * 8 + 4]);
            const float a4[4] = {a.x, a.y, a.z, a.w};
            const float w8[8] = {wl.x, wl.y, wl.z, wl.w, wh.x, wh.y, wh.z, wh.w};
#pragma unroll
            for (int i = 0; i < 4; ++i)
#pragma unroll
                for (int j = 0; j < 8; ++j)
                    acc[i][j] = fmaf(a4[i], w8[j], acc[i][j]);
        }
    }

#pragma unroll
    for (int j = 0; j < 8; ++j) {
        const float cj = c1[tx * 8 + j];
#pragma unroll
        for (int i = 0; i < 4; ++i) {
            const float v = acc[i][j] + cj;
            Ht[tx * 8 + j][ty * 4 + i] = v > 0.f ? v : 0.f;
            acc[i][j] = 0.f;
        }
    }

    // ---------------- layer 2: K = 128 ----------------
    for (int k0 = 0; k0 < 128; k0 += 16) {
        const float* wp = &U2[(k0 + wrow) * 128 + wcol];
        const float4 w0 = *reinterpret_cast<const float4*>(wp);
        const float4 w1 = *reinterpret_cast<const float4*>(wp + 4);
        __syncthreads();
        *reinterpret_cast<float4*>(&Wt[wrow][wcol])     = w0;
        *reinterpret_cast<float4*>(&Wt[wrow][wcol + 4]) = w1;
        __syncthreads();

#pragma unroll
        for (int kk = 0; kk < 16; ++kk) {
            const float4 a  = *reinterpret_cast<const float4*>(&Ht[k0 + kk][ty * 4]);
            const float4 wl = *reinterpret_cast<const float4*>(&Wt[kk][tx * 8]);
            const float4 wh = *reinterpret_cast<const float4*>(&Wt[kk][tx * 8 + 4]);
            const float a4[4] = {a.x, a.y, a.z, a.w};
            const float w8[8] = {wl.x, wl.y, wl.z, wl.w, wh.x, wh.y, wh.z, wh.w};
#pragma unroll
            for (int i = 0; i < 4; ++i)
#pragma unroll
                for (int j = 0; j < 8; ++j)
                    acc[i][j] = fmaf(a4[i], w8[j], acc[i][j]);
        }
    }

    // bias + store (overwrites agg rows owned by this block only)
#pragma unroll
    for (int i = 0; i < 4; ++i) {
        const int n = n0 + ty * 4 + i;
        if (n < NN) {
            float* op = &out[(long long)n * 128 + tx * 8];
#pragma unroll
            for (int j = 0; j < 8; ++j)
                op[j] = acc[i][j] + c2[tx * 8 + j];
        }
    }
}

extern "C" void kernel_launch(void* const* d_in, const int* in_sizes, int n_in,
                              void* d_out, int out_size, void* d_ws, size_t ws_size,
                              hipStream_t stream) {
    const float* x  = (const float*)d_in[0];
    const float* pe = (const float*)d_in[1];
    const float* W1 = (const float*)d_in[2];
    const float* b1 = (const float*)d_in[3];
    const float* W2 = (const float*)d_in[4];
    const float* b2 = (const float*)d_in[5];
    const float* U1 = (const float*)d_in[6];
    const float* c1 = (const float*)d_in[7];
    const float* U2 = (const float*)d_in[8];
    const float* c2 = (const float*)d_in[9];
    const int*   ei = (const int*)d_in[10];
    float* out = (float*)d_out;

    // zero the aggregation buffer (d_out doubles as agg scratch)
    hipMemsetAsync(out, 0, (size_t)NN * 128 * sizeof(float), stream);

    edge_msg_kernel<<<NE / BE, 256, 0, stream>>>(x, pe, W1, b1, W2, b2, ei, out);
    node_upd_kernel<<<(NN + BE - 1) / BE, 256, 0, stream>>>(x, U1, c1, U2, c2, out);
}

// Round 2
// 1366.793 us; speedup vs baseline: 2.2625x; 2.2625x over previous
//
#include <hip/hip_runtime.h>

#define NN 50000
#define NE 800000

typedef __attribute__((ext_vector_type(8))) short bf16x8;
typedef __attribute__((ext_vector_type(4))) float f32x4;

__device__ __forceinline__ unsigned short f2bf(float f) {
    union { float f; unsigned u; } v; v.f = f;
    unsigned r = v.u + 0x7FFFu + ((v.u >> 16) & 1u);
    return (unsigned short)(r >> 16);
}

__device__ __forceinline__ uint2 pack4(float a, float b, float c, float d) {
    uint2 p;
    p.x = (unsigned)f2bf(a) | ((unsigned)f2bf(b) << 16);
    p.y = (unsigned)f2bf(c) | ((unsigned)f2bf(d) << 16);
    return p;
}

// ---------------------------------------------------------------------------
// Weight prep: convert W[K][128] f32 -> bf16 fragments of W^T (A-operand).
// Fragment layout per (mtile,ktile): [64 lanes][8 bf16]; element (m,k):
//   lane = (m&15) | (((k&31)>>3)<<4), i = k&7.
// ws layout (ushort units): W1T @0 (8*6*512), W2T @24576 (8*4*512),
//                           U1T @40960 (8*8*512), U2T @73728 (8*4*512)
// ---------------------------------------------------------------------------
__global__ void prep_weights(const float* __restrict__ W1, const float* __restrict__ W2,
                             const float* __restrict__ U1, const float* __restrict__ U2,
                             unsigned short* __restrict__ ws) {
    int tid = blockIdx.x * blockDim.x + threadIdx.x;
    const float* src; unsigned short* dst; int K;
    if (tid < 6144)        { src = W1; dst = ws;         K = 192; }
    else if (tid < 10240)  { tid -= 6144;  src = W2; dst = ws + 24576; K = 128; }
    else if (tid < 18432)  { tid -= 10240; src = U1; dst = ws + 40960; K = 256; }
    else if (tid < 22528)  { tid -= 18432; src = U2; dst = ws + 73728; K = 128; }
    else return;
    const int m = tid & 127, k = (tid >> 7) * 4;
    const int KT = K >> 5;
    uint2 p = pack4(src[(k + 0) * 128 + m], src[(k + 1) * 128 + m],
                    src[(k + 2) * 128 + m], src[(k + 3) * 128 + m]);
    const int mt = m >> 4, kt = k >> 5, lane = (m & 15) + (((k & 31) >> 3) << 4);
    const int off = (((mt * KT + kt) << 9) + (lane << 3) + ((k & 4) ? 4 : 0));
    *reinterpret_cast<uint2*>(dst + off) = p;
}

// ---------------------------------------------------------------------------
// Edge kernel (transposed MFMA MLP):
//   D1 = W1^T (128x192) . A^T (192x64)  -> H^T = relu(D1 + b1)
//   D2 = W2^T (128x128) . H^T (128x64)  -> msg^T; atomicAdd(agg[dst], msg+b2)
// Block = 256 thr = 4 waves; wave w owns output mtiles {2w, 2w+1} (32 cols).
// ---------------------------------------------------------------------------
__global__ __launch_bounds__(256)
void edge_kernel(const float* __restrict__ x,
                 const float* __restrict__ pe,
                 const float* __restrict__ b1,
                 const float* __restrict__ b2,
                 const int*   __restrict__ ei,
                 const unsigned short* __restrict__ wf,
                 float* __restrict__ agg)
{
    __shared__ __align__(16) unsigned char smem[24576 + 16384];
    unsigned char* Asw = smem;          // [6 kt][4 nt][64][16B]
    unsigned char* Hsw = smem + 24576;  // [4 kt][4 nt][64][16B]

    const int t = threadIdx.x;
    const int l = t & 63;
    const int w = t >> 6;
    const int g = l >> 4;

    bf16x8 w1r[2][6], w2r[2][4];
    {
        const bf16x8* wp1 = reinterpret_cast<const bf16x8*>(wf);
        const bf16x8* wp2 = reinterpret_cast<const bf16x8*>(wf + 24576);
#pragma unroll
        for (int dm = 0; dm < 2; ++dm) {
            const int mt = 2 * w + dm;
#pragma unroll
            for (int kt = 0; kt < 6; ++kt) w1r[dm][kt] = wp1[(mt * 6 + kt) * 64 + l];
#pragma unroll
            for (int kt = 0; kt < 4; ++kt) w2r[dm][kt] = wp2[(mt * 4 + kt) * 64 + l];
        }
    }
    float4 b1v[2], b2v[2];
#pragma unroll
    for (int dm = 0; dm < 2; ++dm) {
        b1v[dm] = *reinterpret_cast<const float4*>(&b1[32 * w + 16 * dm + 4 * g]);
        b2v[dm] = *reinterpret_cast<const float4*>(&b2[32 * w + 16 * dm + 4 * g]);
    }

    const int le = t >> 2;        // staging edge 0..63
    const int lq = (t & 3) * 4;   // staging k base
    const int nt_s = le >> 4;

    for (int tile = blockIdx.x * 5; tile < blockIdx.x * 5 + 5; ++tile) {
        const int e0 = tile * 64;

        // ---- stage A^T (bf16, B-fragment layout) ----
        const int src = ei[e0 + le];
#pragma unroll
        for (int j = 0; j < 12; ++j) {
            const int k = lq + 16 * j;
            float4 av;
            if (j < 8) av = *reinterpret_cast<const float4*>(&x[src * 128 + k]);
            else       av = *reinterpret_cast<const float4*>(&pe[(e0 + le) * 64 + (k - 128)]);
            const int kt = k >> 5;
            const int lane = (le & 15) + (((k & 31) >> 3) << 4);
            const int off = ((kt * 4 + nt_s) << 10) + (lane << 4) + ((k & 4) << 1);
            *reinterpret_cast<uint2*>(Asw + off) = pack4(av.x, av.y, av.z, av.w);
        }
        int dstv[4];
#pragma unroll
        for (int nt = 0; nt < 4; ++nt)
            dstv[nt] = ei[NE + e0 + nt * 16 + (l & 15)];

        __syncthreads();

        // ---- layer 1: K=192 ----
        f32x4 acc[2][4];
#pragma unroll
        for (int dm = 0; dm < 2; ++dm)
#pragma unroll
            for (int nt = 0; nt < 4; ++nt) acc[dm][nt] = (f32x4){0.f, 0.f, 0.f, 0.f};
#pragma unroll
        for (int kt = 0; kt < 6; ++kt) {
            bf16x8 af[4];
#pragma unroll
            for (int nt = 0; nt < 4; ++nt)
                af[nt] = *reinterpret_cast<const bf16x8*>(Asw + ((kt * 4 + nt) << 10) + (l << 4));
#pragma unroll
            for (int nt = 0; nt < 4; ++nt) {
                acc[0][nt] = __builtin_amdgcn_mfma_f32_16x16x32_bf16(w1r[0][kt], af[nt], acc[0][nt], 0, 0, 0);
                acc[1][nt] = __builtin_amdgcn_mfma_f32_16x16x32_bf16(w1r[1][kt], af[nt], acc[1][nt], 0, 0, 0);
            }
        }

        // ---- bias + relu -> H^T in LDS (layer-2 B-frag layout) ----
#pragma unroll
        for (int dm = 0; dm < 2; ++dm) {
            const float bb[4] = {b1v[dm].x, b1v[dm].y, b1v[dm].z, b1v[dm].w};
            const int lane2 = (l & 15) + ((2 * dm + (g >> 1)) << 4);
#pragma unroll
            for (int nt = 0; nt < 4; ++nt) {
                float v0 = acc[dm][nt][0] + bb[0]; v0 = v0 > 0.f ? v0 : 0.f;
                float v1 = acc[dm][nt][1] + bb[1]; v1 = v1 > 0.f ? v1 : 0.f;
                float v2 = acc[dm][nt][2] + bb[2]; v2 = v2 > 0.f ? v2 : 0.f;
                float v3 = acc[dm][nt][3] + bb[3]; v3 = v3 > 0.f ? v3 : 0.f;
                const int off = ((w * 4 + nt) << 10) + (lane2 << 4) + ((g & 1) << 3);
                *reinterpret_cast<uint2*>(Hsw + off) = pack4(v0, v1, v2, v3);
            }
        }
        __syncthreads();

        // ---- layer 2: K=128 ----
        f32x4 acc2[2][4];
#pragma unroll
        for (int dm = 0; dm < 2; ++dm)
#pragma unroll
            for (int nt = 0; nt < 4; ++nt) acc2[dm][nt] = (f32x4){0.f, 0.f, 0.f, 0.f};
#pragma unroll
        for (int kt = 0; kt < 4; ++kt) {
            bf16x8 hf[4];
#pragma unroll
            for (int nt = 0; nt < 4; ++nt)
                hf[nt] = *reinterpret_cast<const bf16x8*>(Hsw + ((kt * 4 + nt) << 10) + (l << 4));
#pragma unroll
            for (int nt = 0; nt < 4; ++nt) {
                acc2[0][nt] = __builtin_amdgcn_mfma_f32_16x16x32_bf16(w2r[0][kt], hf[nt], acc2[0][nt], 0, 0, 0);
                acc2[1][nt] = __builtin_amdgcn_mfma_f32_16x16x32_bf16(w2r[1][kt], hf[nt], acc2[1][nt], 0, 0, 0);
            }
        }

        // ---- bias + atomic scatter (msg^T: m = out col, n = edge) ----
#pragma unroll
        for (int dm = 0; dm < 2; ++dm) {
            const float bb[4] = {b2v[dm].x, b2v[dm].y, b2v[dm].z, b2v[dm].w};
            const int mbase = 32 * w + 16 * dm + 4 * g;
#pragma unroll
            for (int nt = 0; nt < 4; ++nt) {
                float* ap = &agg[dstv[nt] * 128 + mbase];
                atomicAdd(ap + 0, acc2[dm][nt][0] + bb[0]);
                atomicAdd(ap + 1, acc2[dm][nt][1] + bb[1]);
                atomicAdd(ap + 2, acc2[dm][nt][2] + bb[2]);
                atomicAdd(ap + 3, acc2[dm][nt][3] + bb[3]);
            }
        }
    }
}

// ---------------------------------------------------------------------------
// Node kernel: upd_in = [x | agg] (K=256); out = relu(upd_in.U1+c1).U2 + c2
// Same transposed-MFMA structure; agg lives in `out` (in-place safe: block
// reads only its own 64 rows before overwriting them).
// ---------------------------------------------------------------------------
__global__ __launch_bounds__(256)
void node_kernel(const float* __restrict__ x,
                 const float* __restrict__ c1,
                 const float* __restrict__ c2,
                 const unsigned short* __restrict__ wf,
                 float* __restrict__ out)
{
    __shared__ __align__(16) unsigned char smem[32768 + 16384];
    unsigned char* Asw = smem;          // [8 kt][4 nt][64][16B]
    unsigned char* Hsw = smem + 32768;  // [4 kt][4 nt][64][16B]

    const int t = threadIdx.x;
    const int l = t & 63;
    const int w = t >> 6;
    const int g = l >> 4;

    bf16x8 u1r[2][8], u2r[2][4];
    {
        const bf16x8* up1 = reinterpret_cast<const bf16x8*>(wf + 40960);
        const bf16x8* up2 = reinterpret_cast<const bf16x8*>(wf + 73728);
#pragma unroll
        for (int dm = 0; dm < 2; ++dm) {
            const int mt = 2 * w + dm;
#pragma unroll
            for (int kt = 0; kt < 8; ++kt) u1r[dm][kt] = up1[(mt * 8 + kt) * 64 + l];
#pragma unroll
            for (int kt = 0; kt < 4; ++kt) u2r[dm][kt] = up2[(mt * 4 + kt) * 64 + l];
        }
    }
    float4 c1v[2], c2v[2];
#pragma unroll
    for (int dm = 0; dm < 2; ++dm) {
        c1v[dm] = *reinterpret_cast<const float4*>(&c1[32 * w + 16 * dm + 4 * g]);
        c2v[dm] = *reinterpret_cast<const float4*>(&c2[32 * w + 16 * dm + 4 * g]);
    }

    const int n0 = blockIdx.x * 64;
    const int le = t >> 2;
    const int lq = (t & 3) * 4;
    const int nt_s = le >> 4;
    const int node = n0 + le;
    const bool valid = node < NN;

    // ---- stage [x | agg]^T ----
#pragma unroll
    for (int j = 0; j < 16; ++j) {
        const int k = lq + 16 * j;
        float4 av = make_float4(0.f, 0.f, 0.f, 0.f);
        if (valid) {
            if (j < 8) av = *reinterpret_cast<const float4*>(&x[node * 128 + k]);
            else       av = *reinterpret_cast<const float4*>(&out[node * 128 + (k - 128)]);
        }
        const int kt = k >> 5;
        const int lane = (le & 15) + (((k & 31) >> 3) << 4);
        const int off = ((kt * 4 + nt_s) << 10) + (lane << 4) + ((k & 4) << 1);
        *reinterpret_cast<uint2*>(Asw + off) = pack4(av.x, av.y, av.z, av.w);
    }
    __syncthreads();

    // ---- layer 1: K=256 ----
    f32x4 acc[2][4];
#pragma unroll
    for (int dm = 0; dm < 2; ++dm)
#pragma unroll
        for (int nt = 0; nt < 4; ++nt) acc[dm][nt] = (f32x4){0.f, 0.f, 0.f, 0.f};
#pragma unroll
    for (int kt = 0; kt < 8; ++kt) {
        bf16x8 af[4];
#pragma unroll
        for (int nt = 0; nt < 4; ++nt)
            af[nt] = *reinterpret_cast<const bf16x8*>(Asw + ((kt * 4 + nt) << 10) + (l << 4));
#pragma unroll
        for (int nt = 0; nt < 4; ++nt) {
            acc[0][nt] = __builtin_amdgcn_mfma_f32_16x16x32_bf16(u1r[0][kt], af[nt], acc[0][nt], 0, 0, 0);
            acc[1][nt] = __builtin_amdgcn_mfma_f32_16x16x32_bf16(u1r[1][kt], af[nt], acc[1][nt], 0, 0, 0);
        }
    }

#pragma unroll
    for (int dm = 0; dm < 2; ++dm) {
        const float bb[4] = {c1v[dm].x, c1v[dm].y, c1v[dm].z, c1v[dm].w};
        const int lane2 = (l & 15) + ((2 * dm + (g >> 1)) << 4);
#pragma unroll
        for (int nt = 0; nt < 4; ++nt) {
            float v0 = acc[dm][nt][0] + bb[0]; v0 = v0 > 0.f ? v0 : 0.f;
            float v1 = acc[dm][nt][1] + bb[1]; v1 = v1 > 0.f ? v1 : 0.f;
            float v2 = acc[dm][nt][2] + bb[2]; v2 = v2 > 0.f ? v2 : 0.f;
            float v3 = acc[dm][nt][3] + bb[3]; v3 = v3 > 0.f ? v3 : 0.f;
            const int off = ((w * 4 + nt) << 10) + (lane2 << 4) + ((g & 1) << 3);
            *reinterpret_cast<uint2*>(Hsw + off) = pack4(v0, v1, v2, v3);
        }
    }
    __syncthreads();

    // ---- layer 2: K=128 ----
    f32x4 acc2[2][4];
#pragma unroll
    for (int dm = 0; dm < 2; ++dm)
#pragma unroll
        for (int nt = 0; nt < 4; ++nt) acc2[dm][nt] = (f32x4){0.f, 0.f, 0.f, 0.f};
#pragma unroll
    for (int kt = 0; kt < 4; ++kt) {
        bf16x8 hf[4];
#pragma unroll
        for (int nt = 0; nt < 4; ++nt)
            hf[nt] = *reinterpret_cast<const bf16x8*>(Hsw + ((kt * 4 + nt) << 10) + (l << 4));
#pragma unroll
        for (int nt = 0; nt < 4; ++nt) {
            acc2[0][nt] = __builtin_amdgcn_mfma_f32_16x16x32_bf16(u2r[0][kt], hf[nt], acc2[0][nt], 0, 0, 0);
            acc2[1][nt] = __builtin_amdgcn_mfma_f32_16x16x32_bf16(u2r[1][kt], hf[nt], acc2[1][nt], 0, 0, 0);
        }
    }

    // ---- bias + store (out^T frags -> row-major out) ----
#pragma unroll
    for (int dm = 0; dm < 2; ++dm) {
        const int mbase = 32 * w + 16 * dm + 4 * g;
#pragma unroll
        for (int nt = 0; nt < 4; ++nt) {
            const int n = n0 + nt * 16 + (l & 15);
            if (n < NN) {
                float4 o;
                o.x = acc2[dm][nt][0] + c2v[dm].x;
                o.y = acc2[dm][nt][1] + c2v[dm].y;
                o.z = acc2[dm][nt][2] + c2v[dm].z;
                o.w = acc2[dm][nt][3] + c2v[dm].w;
                *reinterpret_cast<float4*>(&out[n * 128 + mbase]) = o;
            }
        }
    }
}

extern "C" void kernel_launch(void* const* d_in, const int* in_sizes, int n_in,
                              void* d_out, int out_size, void* d_ws, size_t ws_size,
                              hipStream_t stream) {
    const float* x  = (const float*)d_in[0];
    const float* pe = (const float*)d_in[1];
    const float* W1 = (const float*)d_in[2];
    const float* b1 = (const float*)d_in[3];
    const float* W2 = (const float*)d_in[4];
    const float* b2 = (const float*)d_in[5];
    const float* U1 = (const float*)d_in[6];
    const float* c1 = (const float*)d_in[7];
    const float* U2 = (const float*)d_in[8];
    const float* c2 = (const float*)d_in[9];
    const int*   ei = (const int*)d_in[10];
    float* out = (float*)d_out;
    unsigned short* wf = (unsigned short*)d_ws;

    prep_weights<<<88, 256, 0, stream>>>(W1, W2, U1, U2, wf);
    hipMemsetAsync(out, 0, (size_t)NN * 128 * sizeof(float), stream);
    edge_kernel<<<NE / 64 / 5, 256, 0, stream>>>(x, pe, b1, b2, ei, wf, out);
    node_kernel<<<(NN + 63) / 64, 256, 0, stream>>>(x, c1, c2, wf, out);
}

// Round 3
// 445.970 us; speedup vs baseline: 6.9340x; 3.0648x over previous
//
#include <hip/hip_runtime.h>

#define NN 50000
#define NE 800000

typedef __attribute__((ext_vector_type(8))) short bf16x8;
typedef __attribute__((ext_vector_type(4))) float f32x4;

__device__ __forceinline__ unsigned short f2bf(float f) {
    union { float f; unsigned u; } v; v.f = f;
    unsigned r = v.u + 0x7FFFu + ((v.u >> 16) & 1u);
    return (unsigned short)(r >> 16);
}

__device__ __forceinline__ uint2 pack4(float a, float b, float c, float d) {
    uint2 p;
    p.x = (unsigned)f2bf(a) | ((unsigned)f2bf(b) << 16);
    p.y = (unsigned)f2bf(c) | ((unsigned)f2bf(d) << 16);
    return p;
}

// ---------------------------------------------------------------------------
// Weight prep: W[K][128] f32 -> bf16 A-operand fragments of W^T.
// ws layout (ushort units): W1T @0, W2T @24576, U1T @40960, U2T @73728
// ---------------------------------------------------------------------------
__global__ void prep_weights(const float* __restrict__ W1, const float* __restrict__ W2,
                             const float* __restrict__ U1, const float* __restrict__ U2,
                             unsigned short* __restrict__ ws) {
    int tid = blockIdx.x * blockDim.x + threadIdx.x;
    const float* src; unsigned short* dst; int K;
    if (tid < 6144)        { src = W1; dst = ws;         K = 192; }
    else if (tid < 10240)  { tid -= 6144;  src = W2; dst = ws + 24576; K = 128; }
    else if (tid < 18432)  { tid -= 10240; src = U1; dst = ws + 40960; K = 256; }
    else if (tid < 22528)  { tid -= 18432; src = U2; dst = ws + 73728; K = 128; }
    else return;
    const int m = tid & 127, k = (tid >> 7) * 4;
    const int KT = K >> 5;
    uint2 p = pack4(src[(k + 0) * 128 + m], src[(k + 1) * 128 + m],
                    src[(k + 2) * 128 + m], src[(k + 3) * 128 + m]);
    const int mt = m >> 4, kt = k >> 5, lane = (m & 15) + (((k & 31) >> 3) << 4);
    const int off = (((mt * KT + kt) << 9) + (lane << 3) + ((k & 4) ? 4 : 0));
    *reinterpret_cast<uint2*>(dst + off) = p;
}

// ---------------------------------------------------------------------------
// CSR build
// ---------------------------------------------------------------------------
__global__ void hist_kernel(const int* __restrict__ ei, int* __restrict__ counts) {
    const int e = blockIdx.x * blockDim.x + threadIdx.x;
    if (e < NE) atomicAdd(&counts[ei[NE + e]], 1);
}

__global__ __launch_bounds__(1024)
void scan_kernel(const int* __restrict__ counts, int* __restrict__ offs,
                 int* __restrict__ cursor) {
    __shared__ int wsum[16];
    __shared__ int carry;
    const int t = threadIdx.x, lane = t & 63, w = t >> 6;
    if (t == 0) carry = 0;
    __syncthreads();
    for (int c = 0; c < (NN + 1023) / 1024; ++c) {
        const int i = c * 1024 + t;
        const int v = (i < NN) ? counts[i] : 0;
        int s = v;
#pragma unroll
        for (int d = 1; d < 64; d <<= 1) {
            int u = __shfl_up(s, d, 64);
            if (lane >= d) s += u;
        }
        if (lane == 63) wsum[w] = s;
        __syncthreads();
        if (t == 0) {
            int a = carry;
#pragma unroll
            for (int k = 0; k < 16; ++k) { int tmp = wsum[k]; wsum[k] = a; a += tmp; }
            carry = a;
        }
        __syncthreads();
        const int excl = wsum[w] + s - v;
        if (i < NN) { offs[i] = excl; cursor[i] = excl; }
        __syncthreads();
    }
}

__global__ void fill_kernel(const int* __restrict__ ei, int* __restrict__ cursor,
                            int* __restrict__ perm) {
    const int e = blockIdx.x * blockDim.x + threadIdx.x;
    if (e < NE) {
        const int p = atomicAdd(&cursor[ei[NE + e]], 1);
        perm[p] = e;
    }
}

// ---------------------------------------------------------------------------
// Edge kernel: H^T = relu(W1^T.A^T + b1); msg^T = W2^T.H^T + b2.
// STORE=1: write msg rows (bf16) to scratch. STORE=0: fp32 atomic scatter.
// ---------------------------------------------------------------------------
template <int STORE>
__global__ __launch_bounds__(256)
void edge_kernel(const float* __restrict__ x,
                 const float* __restrict__ pe,
                 const float* __restrict__ b1,
                 const float* __restrict__ b2,
                 const int*   __restrict__ ei,
                 const unsigned short* __restrict__ wf,
                 float* __restrict__ agg,
                 unsigned short* __restrict__ msg)
{
    __shared__ __align__(16) unsigned char smem[24576 + 16384];
    unsigned char* Asw = smem;
    unsigned char* Hsw = smem + 24576;

    const int t = threadIdx.x;
    const int l = t & 63;
    const int w = t >> 6;
    const int g = l >> 4;

    bf16x8 w1r[2][6], w2r[2][4];
    {
        const bf16x8* wp1 = reinterpret_cast<const bf16x8*>(wf);
        const bf16x8* wp2 = reinterpret_cast<const bf16x8*>(wf + 24576);
#pragma unroll
        for (int dm = 0; dm < 2; ++dm) {
            const int mt = 2 * w + dm;
#pragma unroll
            for (int kt = 0; kt < 6; ++kt) w1r[dm][kt] = wp1[(mt * 6 + kt) * 64 + l];
#pragma unroll
            for (int kt = 0; kt < 4; ++kt) w2r[dm][kt] = wp2[(mt * 4 + kt) * 64 + l];
        }
    }
    float4 b1v[2], b2v[2];
#pragma unroll
    for (int dm = 0; dm < 2; ++dm) {
        b1v[dm] = *reinterpret_cast<const float4*>(&b1[32 * w + 16 * dm + 4 * g]);
        b2v[dm] = *reinterpret_cast<const float4*>(&b2[32 * w + 16 * dm + 4 * g]);
    }

    const int le = t >> 2;
    const int lq = (t & 3) * 4;
    const int nt_s = le >> 4;

    for (int tile = blockIdx.x * 5; tile < blockIdx.x * 5 + 5; ++tile) {
        const int e0 = tile * 64;

        const int src = ei[e0 + le];
#pragma unroll
        for (int j = 0; j < 12; ++j) {
            const int k = lq + 16 * j;
            float4 av;
            if (j < 8) av = *reinterpret_cast<const float4*>(&x[src * 128 + k]);
            else       av = *reinterpret_cast<const float4*>(&pe[(e0 + le) * 64 + (k - 128)]);
            const int kt = k >> 5;
            const int lane = (le & 15) + (((k & 31) >> 3) << 4);
            const int off = ((kt * 4 + nt_s) << 10) + (lane << 4) + ((k & 4) << 1);
            *reinterpret_cast<uint2*>(Asw + off) = pack4(av.x, av.y, av.z, av.w);
        }
        int dstv[4];
        if constexpr (!STORE) {
#pragma unroll
            for (int nt = 0; nt < 4; ++nt)
                dstv[nt] = ei[NE + e0 + nt * 16 + (l & 15)];
        }

        __syncthreads();

        f32x4 acc[2][4];
#pragma unroll
        for (int dm = 0; dm < 2; ++dm)
#pragma unroll
            for (int nt = 0; nt < 4; ++nt) acc[dm][nt] = (f32x4){0.f, 0.f, 0.f, 0.f};
#pragma unroll
        for (int kt = 0; kt < 6; ++kt) {
            bf16x8 af[4];
#pragma unroll
            for (int nt = 0; nt < 4; ++nt)
                af[nt] = *reinterpret_cast<const bf16x8*>(Asw + ((kt * 4 + nt) << 10) + (l << 4));
#pragma unroll
            for (int nt = 0; nt < 4; ++nt) {
                acc[0][nt] = __builtin_amdgcn_mfma_f32_16x16x32_bf16(w1r[0][kt], af[nt], acc[0][nt], 0, 0, 0);
                acc[1][nt] = __builtin_amdgcn_mfma_f32_16x16x32_bf16(w1r[1][kt], af[nt], acc[1][nt], 0, 0, 0);
            }
        }

#pragma unroll
        for (int dm = 0; dm < 2; ++dm) {
            const float bb[4] = {b1v[dm].x, b1v[dm].y, b1v[dm].z, b1v[dm].w};
            const int lane2 = (l & 15) + ((2 * dm + (g >> 1)) << 4);
#pragma unroll
            for (int nt = 0; nt < 4; ++nt) {
                float v0 = acc[dm][nt][0] + bb[0]; v0 = v0 > 0.f ? v0 : 0.f;
                float v1 = acc[dm][nt][1] + bb[1]; v1 = v1 > 0.f ? v1 : 0.f;
                float v2 = acc[dm][nt][2] + bb[2]; v2 = v2 > 0.f ? v2 : 0.f;
                float v3 = acc[dm][nt][3] + bb[3]; v3 = v3 > 0.f ? v3 : 0.f;
                const int off = ((w * 4 + nt) << 10) + (lane2 << 4) + ((g & 1) << 3);
                *reinterpret_cast<uint2*>(Hsw + off) = pack4(v0, v1, v2, v3);
            }
        }
        __syncthreads();

        f32x4 acc2[2][4];
#pragma unroll
        for (int dm = 0; dm < 2; ++dm)
#pragma unroll
            for (int nt = 0; nt < 4; ++nt) acc2[dm][nt] = (f32x4){0.f, 0.f, 0.f, 0.f};
#pragma unroll
        for (int kt = 0; kt < 4; ++kt) {
            bf16x8 hf[4];
#pragma unroll
            for (int nt = 0; nt < 4; ++nt)
                hf[nt] = *reinterpret_cast<const bf16x8*>(Hsw + ((kt * 4 + nt) << 10) + (l << 4));
#pragma unroll
            for (int nt = 0; nt < 4; ++nt) {
                acc2[0][nt] = __builtin_amdgcn_mfma_f32_16x16x32_bf16(w2r[0][kt], hf[nt], acc2[0][nt], 0, 0, 0);
                acc2[1][nt] = __builtin_amdgcn_mfma_f32_16x16x32_bf16(w2r[1][kt], hf[nt], acc2[1][nt], 0, 0, 0);
            }
        }

#pragma unroll
        for (int dm = 0; dm < 2; ++dm) {
            const float bb[4] = {b2v[dm].x, b2v[dm].y, b2v[dm].z, b2v[dm].w};
            const int mbase = 32 * w + 16 * dm + 4 * g;
#pragma unroll
            for (int nt = 0; nt < 4; ++nt) {
                if constexpr (STORE) {
                    const int e = e0 + nt * 16 + (l & 15);
                    *reinterpret_cast<uint2*>(&msg[(long long)e * 128 + mbase]) =
                        pack4(acc2[dm][nt][0] + bb[0], acc2[dm][nt][1] + bb[1],
                              acc2[dm][nt][2] + bb[2], acc2[dm][nt][3] + bb[3]);
                } else {
                    float* ap = &agg[(long long)dstv[nt] * 128 + mbase];
                    atomicAdd(ap + 0, acc2[dm][nt][0] + bb[0]);
                    atomicAdd(ap + 1, acc2[dm][nt][1] + bb[1]);
                    atomicAdd(ap + 2, acc2[dm][nt][2] + bb[2]);
                    atomicAdd(ap + 3, acc2[dm][nt][3] + bb[3]);
                }
            }
        }
    }
}

// ---------------------------------------------------------------------------
// Aggregate: out[node][:] = sum over CSR edges of msg[e][:] (bf16 -> f32)
// 4 threads per node, 32 cols each.
// ---------------------------------------------------------------------------
__global__ __launch_bounds__(256)
void agg_kernel(const unsigned short* __restrict__ msg,
                const int* __restrict__ perm,
                const int* __restrict__ offs,
                const int* __restrict__ counts,
                float* __restrict__ out)
{
    const int t = threadIdx.x;
    const int node = blockIdx.x * 64 + (t >> 2);
    if (node >= NN) return;
    const int c0 = (t & 3) * 32;
    const int start = offs[node];
    const int cnt = counts[node];

    float acc[32];
#pragma unroll
    for (int i = 0; i < 32; ++i) acc[i] = 0.f;

    for (int j = 0; j < cnt; ++j) {
        const int e = perm[start + j];
        const uint4* mp = reinterpret_cast<const uint4*>(&msg[(long long)e * 128 + c0]);
#pragma unroll
        for (int q = 0; q < 4; ++q) {
            const uint4 u = mp[q];
            const unsigned arr[4] = {u.x, u.y, u.z, u.w};
#pragma unroll
            for (int r = 0; r < 4; ++r) {
                union { unsigned u; float f; } lo, hi;
                lo.u = arr[r] << 16;
                hi.u = arr[r] & 0xFFFF0000u;
                acc[q * 8 + 2 * r]     += lo.f;
                acc[q * 8 + 2 * r + 1] += hi.f;
            }
        }
    }

    float4* op = reinterpret_cast<float4*>(&out[(long long)node * 128 + c0]);
#pragma unroll
    for (int q = 0; q < 8; ++q)
        op[q] = make_float4(acc[4 * q], acc[4 * q + 1], acc[4 * q + 2], acc[4 * q + 3]);
}

// ---------------------------------------------------------------------------
// Node kernel (unchanged): out = relu([x|agg].U1+c1).U2 + c2, in-place on out
// ---------------------------------------------------------------------------
__global__ __launch_bounds__(256)
void node_kernel(const float* __restrict__ x,
                 const float* __restrict__ c1,
                 const float* __restrict__ c2,
                 const unsigned short* __restrict__ wf,
                 float* __restrict__ out)
{
    __shared__ __align__(16) unsigned char smem[32768 + 16384];
    unsigned char* Asw = smem;
    unsigned char* Hsw = smem + 32768;

    const int t = threadIdx.x;
    const int l = t & 63;
    const int w = t >> 6;
    const int g = l >> 4;

    bf16x8 u1r[2][8], u2r[2][4];
    {
        const bf16x8* up1 = reinterpret_cast<const bf16x8*>(wf + 40960);
        const bf16x8* up2 = reinterpret_cast<const bf16x8*>(wf + 73728);
#pragma unroll
        for (int dm = 0; dm < 2; ++dm) {
            const int mt = 2 * w + dm;
#pragma unroll
            for (int kt = 0; kt < 8; ++kt) u1r[dm][kt] = up1[(mt * 8 + kt) * 64 + l];
#pragma unroll
            for (int kt = 0; kt < 4; ++kt) u2r[dm][kt] = up2[(mt * 4 + kt) * 64 + l];
        }
    }
    float4 c1v[2], c2v[2];
#pragma unroll
    for (int dm = 0; dm < 2; ++dm) {
        c1v[dm] = *reinterpret_cast<const float4*>(&c1[32 * w + 16 * dm + 4 * g]);
        c2v[dm] = *reinterpret_cast<const float4*>(&c2[32 * w + 16 * dm + 4 * g]);
    }

    const int n0 = blockIdx.x * 64;
    const int le = t >> 2;
    const int lq = (t & 3) * 4;
    const int nt_s = le >> 4;
    const int node = n0 + le;
    const bool valid = node < NN;

#pragma unroll
    for (int j = 0; j < 16; ++j) {
        const int k = lq + 16 * j;
        float4 av = make_float4(0.f, 0.f, 0.f, 0.f);
        if (valid) {
            if (j < 8) av = *reinterpret_cast<const float4*>(&x[node * 128 + k]);
            else       av = *reinterpret_cast<const float4*>(&out[node * 128 + (k - 128)]);
        }
        const int kt = k >> 5;
        const int lane = (le & 15) + (((k & 31) >> 3) << 4);
        const int off = ((kt * 4 + nt_s) << 10) + (lane << 4) + ((k & 4) << 1);
        *reinterpret_cast<uint2*>(Asw + off) = pack4(av.x, av.y, av.z, av.w);
    }
    __syncthreads();

    f32x4 acc[2][4];
#pragma unroll
    for (int dm = 0; dm < 2; ++dm)
#pragma unroll
        for (int nt = 0; nt < 4; ++nt) acc[dm][nt] = (f32x4){0.f, 0.f, 0.f, 0.f};
#pragma unroll
    for (int kt = 0; kt < 8; ++kt) {
        bf16x8 af[4];
#pragma unroll
        for (int nt = 0; nt < 4; ++nt)
            af[nt] = *reinterpret_cast<const bf16x8*>(Asw + ((kt * 4 + nt) << 10) + (l << 4));
#pragma unroll
        for (int nt = 0; nt < 4; ++nt) {
            acc[0][nt] = __builtin_amdgcn_mfma_f32_16x16x32_bf16(u1r[0][kt], af[nt], acc[0][nt], 0, 0, 0);
            acc[1][nt] = __builtin_amdgcn_mfma_f32_16x16x32_bf16(u1r[1][kt], af[nt], acc[1][nt], 0, 0, 0);
        }
    }

#pragma unroll
    for (int dm = 0; dm < 2; ++dm) {
        const float bb[4] = {c1v[dm].x, c1v[dm].y, c1v[dm].z, c1v[dm].w};
        const int lane2 = (l & 15) + ((2 * dm + (g >> 1)) << 4);
#pragma unroll
        for (int nt = 0; nt < 4; ++nt) {
            float v0 = acc[dm][nt][0] + bb[0]; v0 = v0 > 0.f ? v0 : 0.f;
            float v1 = acc[dm][nt][1] + bb[1]; v1 = v1 > 0.f ? v1 : 0.f;
            float v2 = acc[dm][nt][2] + bb[2]; v2 = v2 > 0.f ? v2 : 0.f;
            float v3 = acc[dm][nt][3] + bb[3]; v3 = v3 > 0.f ? v3 : 0.f;
            const int off = ((w * 4 + nt) << 10) + (lane2 << 4) + ((g & 1) << 3);
            *reinterpret_cast<uint2*>(Hsw + off) = pack4(v0, v1, v2, v3);
        }
    }
    __syncthreads();

    f32x4 acc2[2][4];
#pragma unroll
    for (int dm = 0; dm < 2; ++dm)
#pragma unroll
        for (int nt = 0; nt < 4; ++nt) acc2[dm][nt] = (f32x4){0.f, 0.f, 0.f, 0.f};
#pragma unroll
    for (int kt = 0; kt < 4; ++kt) {
        bf16x8 hf[4];
#pragma unroll
        for (int nt = 0; nt < 4; ++nt)
            hf[nt] = *reinterpret_cast<const bf16x8*>(Hsw + ((kt * 4 + nt) << 10) + (l << 4));
#pragma unroll
        for (int nt = 0; nt < 4; ++nt) {
            acc2[0][nt] = __builtin_amdgcn_mfma_f32_16x16x32_bf16(u2r[0][kt], hf[nt], acc2[0][nt], 0, 0, 0);
            acc2[1][nt] = __builtin_amdgcn_mfma_f32_16x16x32_bf16(u2r[1][kt], hf[nt], acc2[1][nt], 0, 0, 0);
        }
    }

#pragma unroll
    for (int dm = 0; dm < 2; ++dm) {
        const int mbase = 32 * w + 16 * dm + 4 * g;
#pragma unroll
        for (int nt = 0; nt < 4; ++nt) {
            const int n = n0 + nt * 16 + (l & 15);
            if (n < NN) {
                float4 o;
                o.x = acc2[dm][nt][0] + c2v[dm].x;
                o.y = acc2[dm][nt][1] + c2v[dm].y;
                o.z = acc2[dm][nt][2] + c2v[dm].z;
                o.w = acc2[dm][nt][3] + c2v[dm].w;
                *reinterpret_cast<float4*>(&out[n * 128 + mbase]) = o;
            }
        }
    }
}

extern "C" void kernel_launch(void* const* d_in, const int* in_sizes, int n_in,
                              void* d_out, int out_size, void* d_ws, size_t ws_size,
                              hipStream_t stream) {
    const float* x  = (const float*)d_in[0];
    const float* pe = (const float*)d_in[1];
    const float* W1 = (const float*)d_in[2];
    const float* b1 = (const float*)d_in[3];
    const float* W2 = (const float*)d_in[4];
    const float* b2 = (const float*)d_in[5];
    const float* U1 = (const float*)d_in[6];
    const float* c1 = (const float*)d_in[7];
    const float* U2 = (const float*)d_in[8];
    const float* c2 = (const float*)d_in[9];
    const int*   ei = (const int*)d_in[10];
    float* out = (float*)d_out;

    unsigned short* wf = (unsigned short*)d_ws;
    int* counts = (int*)((char*)d_ws + (1 << 20));
    int* offs   = (int*)((char*)d_ws + (1 << 20) + (256 << 10));
    int* cursor = (int*)((char*)d_ws + (1 << 20) + (512 << 10));
    int* perm   = (int*)((char*)d_ws + (2 << 20));
    unsigned short* msg = (unsigned short*)((char*)d_ws + (8 << 20));

    const size_t REQ = (size_t)(8 << 20) + (size_t)NE * 128 * 2;

    prep_weights<<<88, 256, 0, stream>>>(W1, W2, U1, U2, wf);

    if (ws_size >= REQ) {
        hipMemsetAsync(counts, 0, 50176 * sizeof(int), stream);
        hist_kernel<<<NE / 256, 256, 0, stream>>>(ei, counts);
        scan_kernel<<<1, 1024, 0, stream>>>(counts, offs, cursor);
        fill_kernel<<<NE / 256, 256, 0, stream>>>(ei, cursor, perm);
        edge_kernel<1><<<NE / 64 / 5, 256, 0, stream>>>(x, pe, b1, b2, ei, wf, nullptr, msg);
        agg_kernel<<<(NN + 63) / 64, 256, 0, stream>>>(msg, perm, offs, counts, out);
        node_kernel<<<(NN + 63) / 64, 256, 0, stream>>>(x, c1, c2, wf, out);
    } else {
        hipMemsetAsync(out, 0, (size_t)NN * 128 * sizeof(float), stream);
        edge_kernel<0><<<NE / 64 / 5, 256, 0, stream>>>(x, pe, b1, b2, ei, wf, out, nullptr);
        node_kernel<<<(NN + 63) / 64, 256, 0, stream>>>(x, c1, c2, wf, out);
    }
}

// Round 4
// 357.567 us; speedup vs baseline: 8.6483x; 1.2472x over previous
//
#include <hip/hip_runtime.h>

#define NN 50000
#define NE 800000

typedef __attribute__((ext_vector_type(8))) short bf16x8;
typedef __attribute__((ext_vector_type(4))) float f32x4;

__device__ __forceinline__ unsigned short f2bf(float f) {
    union { float f; unsigned u; } v; v.f = f;
    unsigned r = v.u + 0x7FFFu + ((v.u >> 16) & 1u);
    return (unsigned short)(r >> 16);
}

__device__ __forceinline__ uint2 pack4(float a, float b, float c, float d) {
    uint2 p;
    p.x = (unsigned)f2bf(a) | ((unsigned)f2bf(b) << 16);
    p.y = (unsigned)f2bf(c) | ((unsigned)f2bf(d) << 16);
    return p;
}

// ---------------------------------------------------------------------------
// Weight prep: W[K][128] f32 -> bf16 A-operand fragments of W^T.
// ws layout (ushort units): W1T @0, W2T @24576, U1T @40960, U2T @73728
// ---------------------------------------------------------------------------
__global__ void prep_weights(const float* __restrict__ W1, const float* __restrict__ W2,
                             const float* __restrict__ U1, const float* __restrict__ U2,
                             unsigned short* __restrict__ ws) {
    int tid = blockIdx.x * blockDim.x + threadIdx.x;
    const float* src; unsigned short* dst; int K;
    if (tid < 6144)        { src = W1; dst = ws;         K = 192; }
    else if (tid < 10240)  { tid -= 6144;  src = W2; dst = ws + 24576; K = 128; }
    else if (tid < 18432)  { tid -= 10240; src = U1; dst = ws + 40960; K = 256; }
    else if (tid < 22528)  { tid -= 18432; src = U2; dst = ws + 73728; K = 128; }
    else return;
    const int m = tid & 127, k = (tid >> 7) * 4;
    const int KT = K >> 5;
    uint2 p = pack4(src[(k + 0) * 128 + m], src[(k + 1) * 128 + m],
                    src[(k + 2) * 128 + m], src[(k + 3) * 128 + m]);
    const int mt = m >> 4, kt = k >> 5, lane = (m & 15) + (((k & 31) >> 3) << 4);
    const int off = (((mt * KT + kt) << 9) + (lane << 3) + ((k & 4) ? 4 : 0));
    *reinterpret_cast<uint2*>(dst + off) = p;
}

// x f32 -> bf16 copy (halves per-edge gather bytes)
__global__ void prep_x(const float* __restrict__ x, unsigned short* __restrict__ xb) {
    const int i = (blockIdx.x * blockDim.x + threadIdx.x) * 8;
    if (i >= NN * 128) return;
    const float4 a = *reinterpret_cast<const float4*>(&x[i]);
    const float4 b = *reinterpret_cast<const float4*>(&x[i + 4]);
    const uint2 p0 = pack4(a.x, a.y, a.z, a.w);
    const uint2 p1 = pack4(b.x, b.y, b.z, b.w);
    *reinterpret_cast<uint4*>(&xb[i]) = make_uint4(p0.x, p0.y, p1.x, p1.y);
}

// ---------------------------------------------------------------------------
// CSR build
// ---------------------------------------------------------------------------
__global__ void hist_kernel(const int* __restrict__ ei, int* __restrict__ counts) {
    const int e = blockIdx.x * blockDim.x + threadIdx.x;
    if (e < NE) atomicAdd(&counts[ei[NE + e]], 1);
}

__global__ __launch_bounds__(1024)
void scan_kernel(const int* __restrict__ counts, int* __restrict__ offs,
                 int* __restrict__ cursor) {
    __shared__ int wsum[16];
    __shared__ int carry;
    const int t = threadIdx.x, lane = t & 63, w = t >> 6;
    if (t == 0) carry = 0;
    __syncthreads();
    for (int c = 0; c < (NN + 1023) / 1024; ++c) {
        const int i = c * 1024 + t;
        const int v = (i < NN) ? counts[i] : 0;
        int s = v;
#pragma unroll
        for (int d = 1; d < 64; d <<= 1) {
            int u = __shfl_up(s, d, 64);
            if (lane >= d) s += u;
        }
        if (lane == 63) wsum[w] = s;
        __syncthreads();
        if (t == 0) {
            int a = carry;
#pragma unroll
            for (int k = 0; k < 16; ++k) { int tmp = wsum[k]; wsum[k] = a; a += tmp; }
            carry = a;
        }
        __syncthreads();
        const int excl = wsum[w] + s - v;
        if (i < NN) { offs[i] = excl; cursor[i] = excl; }
        __syncthreads();
    }
}

// csrpos[e] = position of edge e in CSR order (inverse permutation)
__global__ void fill_kernel(const int* __restrict__ ei, int* __restrict__ cursor,
                            int* __restrict__ csrpos) {
    const int e = blockIdx.x * blockDim.x + threadIdx.x;
    if (e < NE) csrpos[e] = atomicAdd(&cursor[ei[NE + e]], 1);
}

// ---------------------------------------------------------------------------
// Edge kernel v2: 512 thr = 8 waves, 1 mtile/wave; aliased LDS (24 KB);
// register-prefetched gather; msg written in CSR row order (bf16).
// XBF=1: x pre-converted to bf16 (xb); XBF=0: gather f32 x.
// ---------------------------------------------------------------------------
template <int XBF>
__global__ __launch_bounds__(512)
void edge_kernel2(const float* __restrict__ x,
                  const unsigned short* __restrict__ xb,
                  const float* __restrict__ pe,
                  const float* __restrict__ b1,
                  const float* __restrict__ b2,
                  const int* __restrict__ ei,
                  const int* __restrict__ csrpos,
                  const unsigned short* __restrict__ wf,
                  unsigned short* __restrict__ msg)
{
    __shared__ __align__(16) unsigned char Asw[24576];   // Hsw aliases [0,16384)

    const int t = threadIdx.x;
    const int l = t & 63;
    const int w = t >> 6;       // wave = mtile
    const int g = l >> 4;

    bf16x8 w1r[6], w2r[4];
    {
        const bf16x8* wp1 = reinterpret_cast<const bf16x8*>(wf);
        const bf16x8* wp2 = reinterpret_cast<const bf16x8*>(wf + 24576);
#pragma unroll
        for (int kt = 0; kt < 6; ++kt) w1r[kt] = wp1[(w * 6 + kt) * 64 + l];
#pragma unroll
        for (int kt = 0; kt < 4; ++kt) w2r[kt] = wp2[(w * 4 + kt) * 64 + l];
    }
    const float4 b1v = *reinterpret_cast<const float4*>(&b1[16 * w + 4 * g]);
    const float4 b2v = *reinterpret_cast<const float4*>(&b2[16 * w + 4 * g]);

    const int le = t >> 3;              // staged edge 0..63
    const int sub = t & 7;              // k-subgroup of 8
    const int nt_s = le >> 4;
    const int lane_s = (le & 15) + ((sub & 3) << 4);

    uint4  rxb[2];
    float4 rxf[4];
    float4 rpf[2];

    const int tile0 = blockIdx.x * 5;

    // prefetch tile 0
    {
        const int e0 = tile0 * 64;
        const int src = ei[e0 + le];
        if constexpr (XBF) {
#pragma unroll
            for (int j = 0; j < 2; ++j)
                rxb[j] = *reinterpret_cast<const uint4*>(&xb[(size_t)src * 128 + sub * 8 + 64 * j]);
        } else {
#pragma unroll
            for (int j = 0; j < 2; ++j) {
                rxf[2 * j]     = *reinterpret_cast<const float4*>(&x[(size_t)src * 128 + sub * 8 + 64 * j]);
                rxf[2 * j + 1] = *reinterpret_cast<const float4*>(&x[(size_t)src * 128 + sub * 8 + 64 * j + 4]);
            }
        }
        rpf[0] = *reinterpret_cast<const float4*>(&pe[(size_t)(e0 + le) * 64 + sub * 8]);
        rpf[1] = *reinterpret_cast<const float4*>(&pe[(size_t)(e0 + le) * 64 + sub * 8 + 4]);
    }

    for (int ti = 0; ti < 5; ++ti) {
        const int tile = tile0 + ti;
        const int e0 = tile * 64;
        int cp[4];
#pragma unroll
        for (int nt = 0; nt < 4; ++nt) cp[nt] = csrpos[e0 + nt * 16 + (l & 15)];

        __syncthreads();   // prev tile's LDS reads complete

        // staged regs -> LDS (B-fragment layout)
        {
#pragma unroll
            for (int j = 0; j < 2; ++j) {
                const int kt = (sub >> 2) + 2 * j;
                const int off = ((kt * 4 + nt_s) << 10) + (lane_s << 4);
                uint4 v;
                if constexpr (XBF) v = rxb[j];
                else {
                    const uint2 p0 = pack4(rxf[2 * j].x, rxf[2 * j].y, rxf[2 * j].z, rxf[2 * j].w);
                    const uint2 p1 = pack4(rxf[2 * j + 1].x, rxf[2 * j + 1].y, rxf[2 * j + 1].z, rxf[2 * j + 1].w);
                    v = make_uint4(p0.x, p0.y, p1.x, p1.y);
                }
                *reinterpret_cast<uint4*>(Asw + off) = v;
            }
            const int ktp = 4 + (sub >> 2);
            const int offp = ((ktp * 4 + nt_s) << 10) + (lane_s << 4);
            const uint2 q0 = pack4(rpf[0].x, rpf[0].y, rpf[0].z, rpf[0].w);
            const uint2 q1 = pack4(rpf[1].x, rpf[1].y, rpf[1].z, rpf[1].w);
            *reinterpret_cast<uint4*>(Asw + offp) = make_uint4(q0.x, q0.y, q1.x, q1.y);
        }

        // prefetch next tile (loads overlap this tile's MFMAs)
        if (ti < 4) {
            const int e0n = e0 + 64;
            const int srcn = ei[e0n + le];
            if constexpr (XBF) {
#pragma unroll
                for (int j = 0; j < 2; ++j)
                    rxb[j] = *reinterpret_cast<const uint4*>(&xb[(size_t)srcn * 128 + sub * 8 + 64 * j]);
            } else {
#pragma unroll
                for (int j = 0; j < 2; ++j) {
                    rxf[2 * j]     = *reinterpret_cast<const float4*>(&x[(size_t)srcn * 128 + sub * 8 + 64 * j]);
                    rxf[2 * j + 1] = *reinterpret_cast<const float4*>(&x[(size_t)srcn * 128 + sub * 8 + 64 * j + 4]);
                }
            }
            rpf[0] = *reinterpret_cast<const float4*>(&pe[(size_t)(e0n + le) * 64 + sub * 8]);
            rpf[1] = *reinterpret_cast<const float4*>(&pe[(size_t)(e0n + le) * 64 + sub * 8 + 4]);
        }

        __syncthreads();   // Asw staged

        // ---- layer 1: K=192 ----
        f32x4 acc[4];
#pragma unroll
        for (int nt = 0; nt < 4; ++nt) acc[nt] = (f32x4){0.f, 0.f, 0.f, 0.f};
#pragma unroll
        for (int kt = 0; kt < 6; ++kt) {
#pragma unroll
            for (int nt = 0; nt < 4; ++nt) {
                const bf16x8 af = *reinterpret_cast<const bf16x8*>(Asw + ((kt * 4 + nt) << 10) + (l << 4));
                acc[nt] = __builtin_amdgcn_mfma_f32_16x16x32_bf16(w1r[kt], af, acc[nt], 0, 0, 0);
            }
        }

        __syncthreads();   // all layer-1 LDS reads done; alias region free

        // ---- bias + relu -> H^T (aliased into Asw) ----
        {
            const int lane2 = (l & 15) + ((2 * (w & 1) + (g >> 1)) << 4);
            const int kt2 = (16 * w + 4 * g) >> 5;
            const int bo = (g & 1) << 3;
#pragma unroll
            for (int nt = 0; nt < 4; ++nt) {
                float v0 = fmaxf(acc[nt][0] + b1v.x, 0.f);
                float v1 = fmaxf(acc[nt][1] + b1v.y, 0.f);
                float v2 = fmaxf(acc[nt][2] + b1v.z, 0.f);
                float v3 = fmaxf(acc[nt][3] + b1v.w, 0.f);
                *reinterpret_cast<uint2*>(Asw + ((kt2 * 4 + nt) << 10) + (lane2 << 4) + bo) =
                    pack4(v0, v1, v2, v3);
            }
        }

        __syncthreads();   // Hsw ready

        // ---- layer 2: K=128 ----
#pragma unroll
        for (int nt = 0; nt < 4; ++nt) acc[nt] = (f32x4){0.f, 0.f, 0.f, 0.f};
#pragma unroll
        for (int kt = 0; kt < 4; ++kt) {
#pragma unroll
            for (int nt = 0; nt < 4; ++nt) {
                const bf16x8 hf = *reinterpret_cast<const bf16x8*>(Asw + ((kt * 4 + nt) << 10) + (l << 4));
                acc[nt] = __builtin_amdgcn_mfma_f32_16x16x32_bf16(w2r[kt], hf, acc[nt], 0, 0, 0);
            }
        }

        // ---- bias + CSR-ordered msg store (bf16) ----
        const int mbase = 16 * w + 4 * g;
#pragma unroll
        for (int nt = 0; nt < 4; ++nt) {
            *reinterpret_cast<uint2*>(&msg[(size_t)cp[nt] * 128 + mbase]) =
                pack4(acc[nt][0] + b2v.x, acc[nt][1] + b2v.y,
                      acc[nt][2] + b2v.z, acc[nt][3] + b2v.w);
        }
    }
}

// ---------------------------------------------------------------------------
// Aggregate: msg rows are CSR-ordered -> purely sequential reads.
// 4 threads per node, 32 cols each.
// ---------------------------------------------------------------------------
__global__ __launch_bounds__(256)
void agg_kernel(const unsigned short* __restrict__ msg,
                const int* __restrict__ offs,
                const int* __restrict__ counts,
                float* __restrict__ out)
{
    const int t = threadIdx.x;
    const int node = blockIdx.x * 64 + (t >> 2);
    if (node >= NN) return;
    const int c0 = (t & 3) * 32;
    const int start = offs[node];
    const int cnt = counts[node];

    float acc[32];
#pragma unroll
    for (int i = 0; i < 32; ++i) acc[i] = 0.f;

    for (int j = 0; j < cnt; ++j) {
        const uint4* mp = reinterpret_cast<const uint4*>(&msg[(size_t)(start + j) * 128 + c0]);
#pragma unroll
        for (int q = 0; q < 4; ++q) {
            const uint4 u = mp[q];
            const unsigned arr[4] = {u.x, u.y, u.z, u.w};
#pragma unroll
            for (int r = 0; r < 4; ++r) {
                union { unsigned u; float f; } lo, hi;
                lo.u = arr[r] << 16;
                hi.u = arr[r] & 0xFFFF0000u;
                acc[q * 8 + 2 * r]     += lo.f;
                acc[q * 8 + 2 * r + 1] += hi.f;
            }
        }
    }

    float4* op = reinterpret_cast<float4*>(&out[(size_t)node * 128 + c0]);
#pragma unroll
    for (int q = 0; q < 8; ++q)
        op[q] = make_float4(acc[4 * q], acc[4 * q + 1], acc[4 * q + 2], acc[4 * q + 3]);
}

// ---------------------------------------------------------------------------
// Node kernel: out = relu([x|agg].U1+c1).U2 + c2, in-place on out
// ---------------------------------------------------------------------------
__global__ __launch_bounds__(256)
void node_kernel(const float* __restrict__ x,
                 const float* __restrict__ c1,
                 const float* __restrict__ c2,
                 const unsigned short* __restrict__ wf,
                 float* __restrict__ out)
{
    __shared__ __align__(16) unsigned char smem[32768 + 16384];
    unsigned char* Asw = smem;
    unsigned char* Hsw = smem + 32768;

    const int t = threadIdx.x;
    const int l = t & 63;
    const int w = t >> 6;
    const int g = l >> 4;

    bf16x8 u1r[2][8], u2r[2][4];
    {
        const bf16x8* up1 = reinterpret_cast<const bf16x8*>(wf + 40960);
        const bf16x8* up2 = reinterpret_cast<const bf16x8*>(wf + 73728);
#pragma unroll
        for (int dm = 0; dm < 2; ++dm) {
            const int mt = 2 * w + dm;
#pragma unroll
            for (int kt = 0; kt < 8; ++kt) u1r[dm][kt] = up1[(mt * 8 + kt) * 64 + l];
#pragma unroll
            for (int kt = 0; kt < 4; ++kt) u2r[dm][kt] = up2[(mt * 4 + kt) * 64 + l];
        }
    }
    float4 c1v[2], c2v[2];
#pragma unroll
    for (int dm = 0; dm < 2; ++dm) {
        c1v[dm] = *reinterpret_cast<const float4*>(&c1[32 * w + 16 * dm + 4 * g]);
        c2v[dm] = *reinterpret_cast<const float4*>(&c2[32 * w + 16 * dm + 4 * g]);
    }

    const int n0 = blockIdx.x * 64;
    const int le = t >> 2;
    const int lq = (t & 3) * 4;
    const int nt_s = le >> 4;
    const int node = n0 + le;
    const bool valid = node < NN;

#pragma unroll
    for (int j = 0; j < 16; ++j) {
        const int k = lq + 16 * j;
        float4 av = make_float4(0.f, 0.f, 0.f, 0.f);
        if (valid) {
            if (j < 8) av = *reinterpret_cast<const float4*>(&x[(size_t)node * 128 + k]);
            else       av = *reinterpret_cast<const float4*>(&out[(size_t)node * 128 + (k - 128)]);
        }
        const int kt = k >> 5;
        const int lane = (le & 15) + (((k & 31) >> 3) << 4);
        const int off = ((kt * 4 + nt_s) << 10) + (lane << 4) + ((k & 4) << 1);
        *reinterpret_cast<uint2*>(Asw + off) = pack4(av.x, av.y, av.z, av.w);
    }
    __syncthreads();

    f32x4 acc[2][4];
#pragma unroll
    for (int dm = 0; dm < 2; ++dm)
#pragma unroll
        for (int nt = 0; nt < 4; ++nt) acc[dm][nt] = (f32x4){0.f, 0.f, 0.f, 0.f};
#pragma unroll
    for (int kt = 0; kt < 8; ++kt) {
        bf16x8 af[4];
#pragma unroll
        for (int nt = 0; nt < 4; ++nt)
            af[nt] = *reinterpret_cast<const bf16x8*>(Asw + ((kt * 4 + nt) << 10) + (l << 4));
#pragma unroll
        for (int nt = 0; nt < 4; ++nt) {
            acc[0][nt] = __builtin_amdgcn_mfma_f32_16x16x32_bf16(u1r[0][kt], af[nt], acc[0][nt], 0, 0, 0);
            acc[1][nt] = __builtin_amdgcn_mfma_f32_16x16x32_bf16(u1r[1][kt], af[nt], acc[1][nt], 0, 0, 0);
        }
    }

#pragma unroll
    for (int dm = 0; dm < 2; ++dm) {
        const float bb[4] = {c1v[dm].x, c1v[dm].y, c1v[dm].z, c1v[dm].w};
        const int lane2 = (l & 15) + ((2 * dm + (g >> 1)) << 4);
#pragma unroll
        for (int nt = 0; nt < 4; ++nt) {
            float v0 = fmaxf(acc[dm][nt][0] + bb[0], 0.f);
            float v1 = fmaxf(acc[dm][nt][1] + bb[1], 0.f);
            float v2 = fmaxf(acc[dm][nt][2] + bb[2], 0.f);
            float v3 = fmaxf(acc[dm][nt][3] + bb[3], 0.f);
            const int off = ((w * 4 + nt) << 10) + (lane2 << 4) + ((g & 1) << 3);
            *reinterpret_cast<uint2*>(Hsw + off) = pack4(v0, v1, v2, v3);
        }
    }
    __syncthreads();

    f32x4 acc2[2][4];
#pragma unroll
    for (int dm = 0; dm < 2; ++dm)
#pragma unroll
        for (int nt = 0; nt < 4; ++nt) acc2[dm][nt] = (f32x4){0.f, 0.f, 0.f, 0.f};
#pragma unroll
    for (int kt = 0; kt < 4; ++kt) {
        bf16x8 hf[4];
#pragma unroll
        for (int nt = 0; nt < 4; ++nt)
            hf[nt] = *reinterpret_cast<const bf16x8*>(Hsw + ((kt * 4 + nt) << 10) + (l << 4));
#pragma unroll
        for (int nt = 0; nt < 4; ++nt) {
            acc2[0][nt] = __builtin_amdgcn_mfma_f32_16x16x32_bf16(u2r[0][kt], hf[nt], acc2[0][nt], 0, 0, 0);
            acc2[1][nt] = __builtin_amdgcn_mfma_f32_16x16x32_bf16(u2r[1][kt], hf[nt], acc2[1][nt], 0, 0, 0);
        }
    }

#pragma unroll
    for (int dm = 0; dm < 2; ++dm) {
        const int mbase = 32 * w + 16 * dm + 4 * g;
#pragma unroll
        for (int nt = 0; nt < 4; ++nt) {
            const int n = n0 + nt * 16 + (l & 15);
            if (n < NN) {
                float4 o;
                o.x = acc2[dm][nt][0] + c2v[dm].x;
                o.y = acc2[dm][nt][1] + c2v[dm].y;
                o.z = acc2[dm][nt][2] + c2v[dm].z;
                o.w = acc2[dm][nt][3] + c2v[dm].w;
                *reinterpret_cast<float4*>(&out[(size_t)n * 128 + mbase]) = o;
            }
        }
    }
}

// ---------------------------------------------------------------------------
// Legacy atomic-scatter edge kernel (fallback if workspace too small)
// ---------------------------------------------------------------------------
__global__ __launch_bounds__(256)
void edge_atomic(const float* __restrict__ x, const float* __restrict__ pe,
                 const float* __restrict__ b1, const float* __restrict__ b2,
                 const int* __restrict__ ei, const unsigned short* __restrict__ wf,
                 float* __restrict__ agg)
{
    __shared__ __align__(16) unsigned char smem[24576 + 16384];
    unsigned char* Asw = smem;
    unsigned char* Hsw = smem + 24576;

    const int t = threadIdx.x;
    const int l = t & 63;
    const int w = t >> 6;
    const int g = l >> 4;

    bf16x8 w1r[2][6], w2r[2][4];
    {
        const bf16x8* wp1 = reinterpret_cast<const bf16x8*>(wf);
        const bf16x8* wp2 = reinterpret_cast<const bf16x8*>(wf + 24576);
#pragma unroll
        for (int dm = 0; dm < 2; ++dm) {
            const int mt = 2 * w + dm;
#pragma unroll
            for (int kt = 0; kt < 6; ++kt) w1r[dm][kt] = wp1[(mt * 6 + kt) * 64 + l];
#pragma unroll
            for (int kt = 0; kt < 4; ++kt) w2r[dm][kt] = wp2[(mt * 4 + kt) * 64 + l];
        }
    }
    float4 b1v[2], b2v[2];
#pragma unroll
    for (int dm = 0; dm < 2; ++dm) {
        b1v[dm] = *reinterpret_cast<const float4*>(&b1[32 * w + 16 * dm + 4 * g]);
        b2v[dm] = *reinterpret_cast<const float4*>(&b2[32 * w + 16 * dm + 4 * g]);
    }

    const int le = t >> 2;
    const int lq = (t & 3) * 4;
    const int nt_s = le >> 4;

    for (int tile = blockIdx.x * 5; tile < blockIdx.x * 5 + 5; ++tile) {
        const int e0 = tile * 64;
        const int src = ei[e0 + le];
#pragma unroll
        for (int j = 0; j < 12; ++j) {
            const int k = lq + 16 * j;
            float4 av;
            if (j < 8) av = *reinterpret_cast<const float4*>(&x[(size_t)src * 128 + k]);
            else       av = *reinterpret_cast<const float4*>(&pe[(size_t)(e0 + le) * 64 + (k - 128)]);
            const int kt = k >> 5;
            const int lane = (le & 15) + (((k & 31) >> 3) << 4);
            const int off = ((kt * 4 + nt_s) << 10) + (lane << 4) + ((k & 4) << 1);
            *reinterpret_cast<uint2*>(Asw + off) = pack4(av.x, av.y, av.z, av.w);
        }
        int dstv[4];
#pragma unroll
        for (int nt = 0; nt < 4; ++nt) dstv[nt] = ei[NE + e0 + nt * 16 + (l & 15)];
        __syncthreads();

        f32x4 acc[2][4];
#pragma unroll
        for (int dm = 0; dm < 2; ++dm)
#pragma unroll
            for (int nt = 0; nt < 4; ++nt) acc[dm][nt] = (f32x4){0.f, 0.f, 0.f, 0.f};
#pragma unroll
        for (int kt = 0; kt < 6; ++kt) {
#pragma unroll
            for (int nt = 0; nt < 4; ++nt) {
                const bf16x8 af = *reinterpret_cast<const bf16x8*>(Asw + ((kt * 4 + nt) << 10) + (l << 4));
                acc[0][nt] = __builtin_amdgcn_mfma_f32_16x16x32_bf16(w1r[0][kt], af, acc[0][nt], 0, 0, 0);
                acc[1][nt] = __builtin_amdgcn_mfma_f32_16x16x32_bf16(w1r[1][kt], af, acc[1][nt], 0, 0, 0);
            }
        }
#pragma unroll
        for (int dm = 0; dm < 2; ++dm) {
            const float bb[4] = {b1v[dm].x, b1v[dm].y, b1v[dm].z, b1v[dm].w};
            const int lane2 = (l & 15) + ((2 * dm + (g >> 1)) << 4);
#pragma unroll
            for (int nt = 0; nt < 4; ++nt) {
                float v0 = fmaxf(acc[dm][nt][0] + bb[0], 0.f);
                float v1 = fmaxf(acc[dm][nt][1] + bb[1], 0.f);
                float v2 = fmaxf(acc[dm][nt][2] + bb[2], 0.f);
                float v3 = fmaxf(acc[dm][nt][3] + bb[3], 0.f);
                const int off = ((w * 4 + nt) << 10) + (lane2 << 4) + ((g & 1) << 3);
                *reinterpret_cast<uint2*>(Hsw + off) = pack4(v0, v1, v2, v3);
            }
        }
        __syncthreads();

        f32x4 acc2[2][4];
#pragma unroll
        for (int dm = 0; dm < 2; ++dm)
#pragma unroll
            for (int nt = 0; nt < 4; ++nt) acc2[dm][nt] = (f32x4){0.f, 0.f, 0.f, 0.f};
#pragma unroll
        for (int kt = 0; kt < 4; ++kt) {
#pragma unroll
            for (int nt = 0; nt < 4; ++nt) {
                const bf16x8 hf = *reinterpret_cast<const bf16x8*>(Hsw + ((kt * 4 + nt) << 10) + (l << 4));
                acc2[0][nt] = __builtin_amdgcn_mfma_f32_16x16x32_bf16(w2r[0][kt], hf, acc2[0][nt], 0, 0, 0);
                acc2[1][nt] = __builtin_amdgcn_mfma_f32_16x16x32_bf16(w2r[1][kt], hf, acc2[1][nt], 0, 0, 0);
            }
        }
#pragma unroll
        for (int dm = 0; dm < 2; ++dm) {
            const float bb[4] = {b2v[dm].x, b2v[dm].y, b2v[dm].z, b2v[dm].w};
            const int mbase = 32 * w + 16 * dm + 4 * g;
#pragma unroll
            for (int nt = 0; nt < 4; ++nt) {
                float* ap = &agg[(size_t)dstv[nt] * 128 + mbase];
                atomicAdd(ap + 0, acc2[dm][nt][0] + bb[0]);
                atomicAdd(ap + 1, acc2[dm][nt][1] + bb[1]);
                atomicAdd(ap + 2, acc2[dm][nt][2] + bb[2]);
                atomicAdd(ap + 3, acc2[dm][nt][3] + bb[3]);
            }
        }
    }
}

extern "C" void kernel_launch(void* const* d_in, const int* in_sizes, int n_in,
                              void* d_out, int out_size, void* d_ws, size_t ws_size,
                              hipStream_t stream) {
    const float* x  = (const float*)d_in[0];
    const float* pe = (const float*)d_in[1];
    const float* W1 = (const float*)d_in[2];
    const float* b1 = (const float*)d_in[3];
    const float* W2 = (const float*)d_in[4];
    const float* b2 = (const float*)d_in[5];
    const float* U1 = (const float*)d_in[6];
    const float* c1 = (const float*)d_in[7];
    const float* U2 = (const float*)d_in[8];
    const float* c2 = (const float*)d_in[9];
    const int*   ei = (const int*)d_in[10];
    float* out = (float*)d_out;

    const size_t MB = 1 << 20;
    unsigned short* wf  = (unsigned short*)d_ws;
    int* counts = (int*)((char*)d_ws + 1 * MB);
    int* offs   = (int*)((char*)d_ws + 1 * MB + 256 * 1024);
    int* cursor = (int*)((char*)d_ws + 1 * MB + 512 * 1024);
    int* csrpos = (int*)((char*)d_ws + 2 * MB);                   // 3.2 MB
    unsigned short* xb   = (unsigned short*)((char*)d_ws + 6 * MB);  // 12.8 MB
    unsigned short* msgA = (unsigned short*)((char*)d_ws + 19 * MB);
    unsigned short* msgB = (unsigned short*)((char*)d_ws + 6 * MB);

    const size_t MSG_BYTES = (size_t)NE * 128 * 2;
    const size_t REQA = 19 * MB + MSG_BYTES;
    const size_t REQB = 6 * MB + MSG_BYTES;

    prep_weights<<<88, 256, 0, stream>>>(W1, W2, U1, U2, wf);

    if (ws_size >= REQB) {
        const bool tierA = ws_size >= REQA;
        unsigned short* msg = tierA ? msgA : msgB;

        hipMemsetAsync(counts, 0, 50176 * sizeof(int), stream);
        if (tierA) prep_x<<<3125, 256, 0, stream>>>(x, xb);
        hist_kernel<<<NE / 256, 256, 0, stream>>>(ei, counts);
        scan_kernel<<<1, 1024, 0, stream>>>(counts, offs, cursor);
        fill_kernel<<<NE / 256, 256, 0, stream>>>(ei, cursor, csrpos);
        if (tierA)
            edge_kernel2<1><<<NE / 64 / 5, 512, 0, stream>>>(x, xb, pe, b1, b2, ei, csrpos, wf, msg);
        else
            edge_kernel2<0><<<NE / 64 / 5, 512, 0, stream>>>(x, nullptr, pe, b1, b2, ei, csrpos, wf, msg);
        agg_kernel<<<(NN + 63) / 64, 256, 0, stream>>>(msg, offs, counts, out);
        node_kernel<<<(NN + 63) / 64, 256, 0, stream>>>(x, c1, c2, wf, out);
    } else {
        hipMemsetAsync(out, 0, (size_t)NN * 128 * sizeof(float), stream);
        edge_atomic<<<NE / 64 / 5, 256, 0, stream>>>(x, pe, b1, b2, ei, wf, out);
        node_kernel<<<(NN + 63) / 64, 256, 0, stream>>>(x, c1, c2, wf, out);
    }
}

// Round 5
// 288.047 us; speedup vs baseline: 10.7356x; 1.2413x over previous
//
#include <hip/hip_runtime.h>

#define NN 50000
#define NE 800000

typedef __attribute__((ext_vector_type(8))) short bf16x8;
typedef __attribute__((ext_vector_type(4))) float f32x4;

// swizzled slot within a 1KB subtile (64 x 16B slots); bijective, applied on
// both write and read so correctness is layout-independent.
#define SWS(s, kt) ((s) ^ (((s) >> 3) & 6) ^ ((kt) & 3))

__device__ __forceinline__ unsigned short f2bf(float f) {
    union { float f; unsigned u; } v; v.f = f;
    unsigned r = v.u + 0x7FFFu + ((v.u >> 16) & 1u);
    return (unsigned short)(r >> 16);
}

__device__ __forceinline__ uint2 pack4(float a, float b, float c, float d) {
    uint2 p;
    p.x = (unsigned)f2bf(a) | ((unsigned)f2bf(b) << 16);
    p.y = (unsigned)f2bf(c) | ((unsigned)f2bf(d) << 16);
    return p;
}

// ---------------------------------------------------------------------------
// Weight prep: W[K][128] f32 -> bf16 A-operand fragments of W^T.
// ws layout (ushort units): W1T @0, W2T @24576, U1T @40960, U2T @73728
// ---------------------------------------------------------------------------
__global__ void prep_weights(const float* __restrict__ W1, const float* __restrict__ W2,
                             const float* __restrict__ U1, const float* __restrict__ U2,
                             unsigned short* __restrict__ ws) {
    int tid = blockIdx.x * blockDim.x + threadIdx.x;
    const float* src; unsigned short* dst; int K;
    if (tid < 6144)        { src = W1; dst = ws;         K = 192; }
    else if (tid < 10240)  { tid -= 6144;  src = W2; dst = ws + 24576; K = 128; }
    else if (tid < 18432)  { tid -= 10240; src = U1; dst = ws + 40960; K = 256; }
    else if (tid < 22528)  { tid -= 18432; src = U2; dst = ws + 73728; K = 128; }
    else return;
    const int m = tid & 127, k = (tid >> 7) * 4;
    const int KT = K >> 5;
    uint2 p = pack4(src[(k + 0) * 128 + m], src[(k + 1) * 128 + m],
                    src[(k + 2) * 128 + m], src[(k + 3) * 128 + m]);
    const int mt = m >> 4, kt = k >> 5, lane = (m & 15) + (((k & 31) >> 3) << 4);
    const int off = (((mt * KT + kt) << 9) + (lane << 3) + ((k & 4) ? 4 : 0));
    *reinterpret_cast<uint2*>(dst + off) = p;
}

// x f32 -> bf16 copy
__global__ void prep_x(const float* __restrict__ x, unsigned short* __restrict__ xb) {
    const int i = (blockIdx.x * blockDim.x + threadIdx.x) * 8;
    if (i >= NN * 128) return;
    const float4 a = *reinterpret_cast<const float4*>(&x[i]);
    const float4 b = *reinterpret_cast<const float4*>(&x[i + 4]);
    const uint2 p0 = pack4(a.x, a.y, a.z, a.w);
    const uint2 p1 = pack4(b.x, b.y, b.z, b.w);
    *reinterpret_cast<uint4*>(&xb[i]) = make_uint4(p0.x, p0.y, p1.x, p1.y);
}

// ---------------------------------------------------------------------------
// CSR build: hist -> 3-kernel parallel scan -> fill (csrpos = inverse perm)
// ---------------------------------------------------------------------------
__global__ void hist_kernel(const int* __restrict__ ei, int* __restrict__ counts) {
    const int e = blockIdx.x * blockDim.x + threadIdx.x;
    if (e < NE) atomicAdd(&counts[ei[NE + e]], 1);
}

__global__ __launch_bounds__(256)
void scan1_kernel(const int* __restrict__ counts, int* __restrict__ offs,
                  int* __restrict__ bsums) {
    __shared__ int wsum[4];
    const int t = threadIdx.x, lane = t & 63, w = t >> 6;
    const int i = blockIdx.x * 256 + t;
    const int v = (i < NN) ? counts[i] : 0;
    int s = v;
#pragma unroll
    for (int d = 1; d < 64; d <<= 1) {
        int u = __shfl_up(s, d, 64);
        if (lane >= d) s += u;
    }
    if (lane == 63) wsum[w] = s;
    __syncthreads();
    if (t == 0) {
        int a = 0;
#pragma unroll
        for (int k = 0; k < 4; ++k) { int tmp = wsum[k]; wsum[k] = a; a += tmp; }
    }
    __syncthreads();
    const int excl = wsum[w] + s - v;
    if (i < NN) offs[i] = excl;
    if (t == 255) bsums[blockIdx.x] = wsum[3] + s;
}

__global__ __launch_bounds__(256)
void scan2_kernel(const int* __restrict__ bsums, int* __restrict__ boffs) {
    __shared__ int wsum[4];
    const int t = threadIdx.x, lane = t & 63, w = t >> 6;
    const int v = (t < 196) ? bsums[t] : 0;
    int s = v;
#pragma unroll
    for (int d = 1; d < 64; d <<= 1) {
        int u = __shfl_up(s, d, 64);
        if (lane >= d) s += u;
    }
    if (lane == 63) wsum[w] = s;
    __syncthreads();
    if (t == 0) {
        int a = 0;
#pragma unroll
        for (int k = 0; k < 4; ++k) { int tmp = wsum[k]; wsum[k] = a; a += tmp; }
    }
    __syncthreads();
    boffs[t] = wsum[w] + s - v;
}

__global__ __launch_bounds__(256)
void scan3_kernel(int* __restrict__ offs, const int* __restrict__ boffs,
                  int* __restrict__ cursor) {
    const int i = blockIdx.x * 256 + threadIdx.x;
    if (i < NN) {
        const int o = offs[i] + boffs[i >> 8];
        offs[i] = o;
        cursor[i] = o;
    }
}

__global__ void fill_kernel(const int* __restrict__ ei, int* __restrict__ cursor,
                            int* __restrict__ csrpos) {
    const int e = blockIdx.x * blockDim.x + threadIdx.x;
    if (e < NE) csrpos[e] = atomicAdd(&cursor[ei[NE + e]], 1);
}

// ---------------------------------------------------------------------------
// Edge kernel: 512 thr = 8 waves, 1 mtile/wave; swizzled LDS; separate Hsw
// (3 syncthreads/tile); register-prefetched gather; CSR-ordered msg store.
// ---------------------------------------------------------------------------
template <int XBF>
__global__ __launch_bounds__(512)
void edge_kernel2(const float* __restrict__ x,
                  const unsigned short* __restrict__ xb,
                  const float* __restrict__ pe,
                  const float* __restrict__ b1,
                  const float* __restrict__ b2,
                  const int* __restrict__ ei,
                  const int* __restrict__ csrpos,
                  const unsigned short* __restrict__ wf,
                  unsigned short* __restrict__ msg)
{
    __shared__ __align__(16) unsigned char Asw[24576];  // 6 kt x 4 nt x 1KB
    __shared__ __align__(16) unsigned char Hsw[16384];  // 4 kt x 4 nt x 1KB

    const int t = threadIdx.x;
    const int l = t & 63;
    const int w = t >> 6;       // wave = mtile
    const int g = l >> 4;

    bf16x8 w1r[6], w2r[4];
    {
        const bf16x8* wp1 = reinterpret_cast<const bf16x8*>(wf);
        const bf16x8* wp2 = reinterpret_cast<const bf16x8*>(wf + 24576);
#pragma unroll
        for (int kt = 0; kt < 6; ++kt) w1r[kt] = wp1[(w * 6 + kt) * 64 + l];
#pragma unroll
        for (int kt = 0; kt < 4; ++kt) w2r[kt] = wp2[(w * 4 + kt) * 64 + l];
    }
    const float4 b1v = *reinterpret_cast<const float4*>(&b1[16 * w + 4 * g]);
    const float4 b2v = *reinterpret_cast<const float4*>(&b2[16 * w + 4 * g]);

    const int le = t >> 3;              // staged edge 0..63
    const int sub = t & 7;              // k-subgroup
    const int nt_s = le >> 4;
    const int lane_s = (le & 15) + ((sub & 3) << 4);

    uint4  rxb[2];
    float4 rxf[4];
    float4 rpf[2];

    const int tile0 = blockIdx.x * 5;

    // prefetch tile 0
    {
        const int e0 = tile0 * 64;
        const int src = ei[e0 + le];
        if constexpr (XBF) {
#pragma unroll
            for (int j = 0; j < 2; ++j)
                rxb[j] = *reinterpret_cast<const uint4*>(&xb[(size_t)src * 128 + sub * 8 + 64 * j]);
        } else {
#pragma unroll
            for (int j = 0; j < 2; ++j) {
                rxf[2 * j]     = *reinterpret_cast<const float4*>(&x[(size_t)src * 128 + sub * 8 + 64 * j]);
                rxf[2 * j + 1] = *reinterpret_cast<const float4*>(&x[(size_t)src * 128 + sub * 8 + 64 * j + 4]);
            }
        }
        rpf[0] = *reinterpret_cast<const float4*>(&pe[(size_t)(e0 + le) * 64 + sub * 8]);
        rpf[1] = *reinterpret_cast<const float4*>(&pe[(size_t)(e0 + le) * 64 + sub * 8 + 4]);
    }

    for (int ti = 0; ti < 5; ++ti) {
        const int e0 = (tile0 + ti) * 64;
        int cp[4];
#pragma unroll
        for (int nt = 0; nt < 4; ++nt) cp[nt] = csrpos[e0 + nt * 16 + (l & 15)];

        __syncthreads();   // prev tile's LDS reads (Asw L1 + Hsw L2) complete

        // staged regs -> Asw (swizzled B-fragment layout)
        {
#pragma unroll
            for (int j = 0; j < 2; ++j) {
                const int kt = (sub >> 2) + 2 * j;
                uint4 v;
                if constexpr (XBF) v = rxb[j];
                else {
                    const uint2 p0 = pack4(rxf[2 * j].x, rxf[2 * j].y, rxf[2 * j].z, rxf[2 * j].w);
                    const uint2 p1 = pack4(rxf[2 * j + 1].x, rxf[2 * j + 1].y, rxf[2 * j + 1].z, rxf[2 * j + 1].w);
                    v = make_uint4(p0.x, p0.y, p1.x, p1.y);
                }
                *reinterpret_cast<uint4*>(Asw + ((kt * 4 + nt_s) << 10) + (SWS(lane_s, kt) << 4)) = v;
            }
            const int ktp = 4 + (sub >> 2);
            const uint2 q0 = pack4(rpf[0].x, rpf[0].y, rpf[0].z, rpf[0].w);
            const uint2 q1 = pack4(rpf[1].x, rpf[1].y, rpf[1].z, rpf[1].w);
            *reinterpret_cast<uint4*>(Asw + ((ktp * 4 + nt_s) << 10) + (SWS(lane_s, ktp) << 4)) =
                make_uint4(q0.x, q0.y, q1.x, q1.y);
        }

        // prefetch next tile (overlaps this tile's MFMAs)
        if (ti < 4) {
            const int e0n = e0 + 64;
            const int srcn = ei[e0n + le];
            if constexpr (XBF) {
#pragma unroll
                for (int j = 0; j < 2; ++j)
                    rxb[j] = *reinterpret_cast<const uint4*>(&xb[(size_t)srcn * 128 + sub * 8 + 64 * j]);
            } else {
#pragma unroll
                for (int j = 0; j < 2; ++j) {
                    rxf[2 * j]     = *reinterpret_cast<const float4*>(&x[(size_t)srcn * 128 + sub * 8 + 64 * j]);
                    rxf[2 * j + 1] = *reinterpret_cast<const float4*>(&x[(size_t)srcn * 128 + sub * 8 + 64 * j + 4]);
                }
            }
            rpf[0] = *reinterpret_cast<const float4*>(&pe[(size_t)(e0n + le) * 64 + sub * 8]);
            rpf[1] = *reinterpret_cast<const float4*>(&pe[(size_t)(e0n + le) * 64 + sub * 8 + 4]);
        }

        __syncthreads();   // Asw staged

        // ---- layer 1: K=192 ----
        f32x4 acc[4];
#pragma unroll
        for (int nt = 0; nt < 4; ++nt) acc[nt] = (f32x4){0.f, 0.f, 0.f, 0.f};
#pragma unroll
        for (int kt = 0; kt < 6; ++kt) {
#pragma unroll
            for (int nt = 0; nt < 4; ++nt) {
                const bf16x8 af = *reinterpret_cast<const bf16x8*>(
                    Asw + ((kt * 4 + nt) << 10) + (SWS(l, kt) << 4));
                acc[nt] = __builtin_amdgcn_mfma_f32_16x16x32_bf16(w1r[kt], af, acc[nt], 0, 0, 0);
            }
        }

        // ---- bias + relu -> Hsw (no WAR hazard: prev Hsw reads fenced above) ----
        {
            const int kt2 = (16 * w + 4 * g) >> 5;
            const int lane2 = (l & 15) + ((2 * (w & 1) + (g >> 1)) << 4);
            const int bo = (g & 1) << 3;
#pragma unroll
            for (int nt = 0; nt < 4; ++nt) {
                float v0 = fmaxf(acc[nt][0] + b1v.x, 0.f);
                float v1 = fmaxf(acc[nt][1] + b1v.y, 0.f);
                float v2 = fmaxf(acc[nt][2] + b1v.z, 0.f);
                float v3 = fmaxf(acc[nt][3] + b1v.w, 0.f);
                *reinterpret_cast<uint2*>(Hsw + ((kt2 * 4 + nt) << 10) + (SWS(lane2, kt2) << 4) + bo) =
                    pack4(v0, v1, v2, v3);
            }
        }

        __syncthreads();   // Hsw ready

        // ---- layer 2: K=128 ----
#pragma unroll
        for (int nt = 0; nt < 4; ++nt) acc[nt] = (f32x4){0.f, 0.f, 0.f, 0.f};
#pragma unroll
        for (int kt = 0; kt < 4; ++kt) {
#pragma unroll
            for (int nt = 0; nt < 4; ++nt) {
                const bf16x8 hf = *reinterpret_cast<const bf16x8*>(
                    Hsw + ((kt * 4 + nt) << 10) + (SWS(l, kt) << 4));
                acc[nt] = __builtin_amdgcn_mfma_f32_16x16x32_bf16(w2r[kt], hf, acc[nt], 0, 0, 0);
            }
        }

        // ---- bias + CSR-ordered msg store ----
        const int mbase = 16 * w + 4 * g;
#pragma unroll
        for (int nt = 0; nt < 4; ++nt) {
            *reinterpret_cast<uint2*>(&msg[(size_t)cp[nt] * 128 + mbase]) =
                pack4(acc[nt][0] + b2v.x, acc[nt][1] + b2v.y,
                      acc[nt][2] + b2v.z, acc[nt][3] + b2v.w);
        }
    }
}

// ---------------------------------------------------------------------------
// Fused node kernel: agg = segment-sum of CSR-ordered msg (f32 regs), then
// out = relu([x|agg].U1+c1).U2 + c2.  512 thr = 8 waves, 64 nodes/block.
// ---------------------------------------------------------------------------
template <int XBF>
__global__ __launch_bounds__(512)
void node_fused(const float* __restrict__ x,
                const unsigned short* __restrict__ xb,
                const float* __restrict__ c1,
                const float* __restrict__ c2,
                const unsigned short* __restrict__ wf,
                const int* __restrict__ offs,
                const int* __restrict__ counts,
                const unsigned short* __restrict__ msg,
                float* __restrict__ out)
{
    __shared__ __align__(16) unsigned char Asw[32768];  // 8 kt x 4 nt x 1KB
    __shared__ __align__(16) unsigned char Hsw[16384];  // 4 kt x 4 nt x 1KB

    const int t = threadIdx.x;
    const int l = t & 63;
    const int w = t >> 6;
    const int g = l >> 4;

    bf16x8 u1r[8], u2r[4];
    {
        const bf16x8* up1 = reinterpret_cast<const bf16x8*>(wf + 40960);
        const bf16x8* up2 = reinterpret_cast<const bf16x8*>(wf + 73728);
#pragma unroll
        for (int kt = 0; kt < 8; ++kt) u1r[kt] = up1[(w * 8 + kt) * 64 + l];
#pragma unroll
        for (int kt = 0; kt < 4; ++kt) u2r[kt] = up2[(w * 4 + kt) * 64 + l];
    }
    const float4 c1v = *reinterpret_cast<const float4*>(&c1[16 * w + 4 * g]);
    const float4 c2v = *reinterpret_cast<const float4*>(&c2[16 * w + 4 * g]);

    const int n0 = blockIdx.x * 64;
    const int le = t >> 3;          // node 0..63
    const int q  = t & 7;           // 16-col group
    const int nt_s = le >> 4;
    const int node = n0 + le;
    const bool valid = node < NN;

    // ---- aggregate msg rows (CSR-contiguous) into f32 registers ----
    float a16[16];
#pragma unroll
    for (int i = 0; i < 16; ++i) a16[i] = 0.f;
    int start = 0, cnt = 0;
    if (valid) { start = offs[node]; cnt = counts[node]; }
    for (int j = 0; j < cnt; ++j) {
        const uint4* mp = reinterpret_cast<const uint4*>(&msg[(size_t)(start + j) * 128 + q * 16]);
        const uint4 u0 = mp[0], u1 = mp[1];
        const unsigned arr[8] = {u0.x, u0.y, u0.z, u0.w, u1.x, u1.y, u1.z, u1.w};
#pragma unroll
        for (int r = 0; r < 8; ++r) {
            union { unsigned u; float f; } lo, hi;
            lo.u = arr[r] << 16;
            hi.u = arr[r] & 0xFFFF0000u;
            a16[2 * r]     += lo.f;
            a16[2 * r + 1] += hi.f;
        }
    }

    // ---- stage x (kt 0..3) ----
#pragma unroll
    for (int i = 0; i < 2; ++i) {
        const int o = 2 * q + i;           // x octet 0..15
        const int kt = o >> 2;
        const int slot = (le & 15) + ((o & 3) << 4);
        uint4 v = make_uint4(0u, 0u, 0u, 0u);
        if (valid) {
            if constexpr (XBF) {
                v = *reinterpret_cast<const uint4*>(&xb[(size_t)node * 128 + o * 8]);
            } else {
                const float4 f0 = *reinterpret_cast<const float4*>(&x[(size_t)node * 128 + o * 8]);
                const float4 f1 = *reinterpret_cast<const float4*>(&x[(size_t)node * 128 + o * 8 + 4]);
                const uint2 p0 = pack4(f0.x, f0.y, f0.z, f0.w);
                const uint2 p1 = pack4(f1.x, f1.y, f1.z, f1.w);
                v = make_uint4(p0.x, p0.y, p1.x, p1.y);
            }
        }
        *reinterpret_cast<uint4*>(Asw + ((kt * 4 + nt_s) << 10) + (SWS(slot, kt) << 4)) = v;
    }

    // ---- stage agg (kt 4..7); cols [16q,16q+16) ----
    {
        const int kt = 4 + (q >> 1);
#pragma unroll
        for (int i = 0; i < 2; ++i) {
            const int j4 = 2 * (q & 1) + i;
            const int slot = (le & 15) + (j4 << 4);
            const uint2 p0 = pack4(a16[8 * i + 0], a16[8 * i + 1], a16[8 * i + 2], a16[8 * i + 3]);
            const uint2 p1 = pack4(a16[8 * i + 4], a16[8 * i + 5], a16[8 * i + 6], a16[8 * i + 7]);
            *reinterpret_cast<uint4*>(Asw + ((kt * 4 + nt_s) << 10) + (SWS(slot, kt) << 4)) =
                make_uint4(p0.x, p0.y, p1.x, p1.y);
        }
    }
    __syncthreads();

    // ---- layer 1: K=256 ----
    f32x4 acc[4];
#pragma unroll
    for (int nt = 0; nt < 4; ++nt) acc[nt] = (f32x4){0.f, 0.f, 0.f, 0.f};
#pragma unroll
    for (int kt = 0; kt < 8; ++kt) {
#pragma unroll
        for (int nt = 0; nt < 4; ++nt) {
            const bf16x8 af = *reinterpret_cast<const bf16x8*>(
                Asw + ((kt * 4 + nt) << 10) + (SWS(l, kt) << 4));
            acc[nt] = __builtin_amdgcn_mfma_f32_16x16x32_bf16(u1r[kt], af, acc[nt], 0, 0, 0);
        }
    }

    // ---- bias + relu -> Hsw ----
    {
        const int kt2 = (16 * w + 4 * g) >> 5;
        const int lane2 = (l & 15) + ((2 * (w & 1) + (g >> 1)) << 4);
        const int bo = (g & 1) << 3;
#pragma unroll
        for (int nt = 0; nt < 4; ++nt) {
            float v0 = fmaxf(acc[nt][0] + c1v.x, 0.f);
            float v1 = fmaxf(acc[nt][1] + c1v.y, 0.f);
            float v2 = fmaxf(acc[nt][2] + c1v.z, 0.f);
            float v3 = fmaxf(acc[nt][3] + c1v.w, 0.f);
            *reinterpret_cast<uint2*>(Hsw + ((kt2 * 4 + nt) << 10) + (SWS(lane2, kt2) << 4) + bo) =
                pack4(v0, v1, v2, v3);
        }
    }
    __syncthreads();

    // ---- layer 2: K=128 ----
    f32x4 a2[4];
#pragma unroll
    for (int nt = 0; nt < 4; ++nt) a2[nt] = (f32x4){0.f, 0.f, 0.f, 0.f};
#pragma unroll
    for (int kt = 0; kt < 4; ++kt) {
#pragma unroll
        for (int nt = 0; nt < 4; ++nt) {
            const bf16x8 hf = *reinterpret_cast<const bf16x8*>(
                Hsw + ((kt * 4 + nt) << 10) + (SWS(l, kt) << 4));
            a2[nt] = __builtin_amdgcn_mfma_f32_16x16x32_bf16(u2r[kt], hf, a2[nt], 0, 0, 0);
        }
    }

    // ---- bias + store ----
    const int mbase = 16 * w + 4 * g;
#pragma unroll
    for (int nt = 0; nt < 4; ++nt) {
        const int n = n0 + nt * 16 + (l & 15);
        if (n < NN) {
            float4 o;
            o.x = a2[nt][0] + c2v.x;
            o.y = a2[nt][1] + c2v.y;
            o.z = a2[nt][2] + c2v.z;
            o.w = a2[nt][3] + c2v.w;
            *reinterpret_cast<float4*>(&out[(size_t)n * 128 + mbase]) = o;
        }
    }
}

// ---------------------------------------------------------------------------
// Legacy fallback (small workspace): atomic scatter edge + in-place node.
// ---------------------------------------------------------------------------
__global__ __launch_bounds__(256)
void edge_atomic(const float* __restrict__ x, const float* __restrict__ pe,
                 const float* __restrict__ b1, const float* __restrict__ b2,
                 const int* __restrict__ ei, const unsigned short* __restrict__ wf,
                 float* __restrict__ agg)
{
    __shared__ __align__(16) unsigned char smem[24576 + 16384];
    unsigned char* Asw = smem;
    unsigned char* Hsw = smem + 24576;

    const int t = threadIdx.x;
    const int l = t & 63;
    const int w = t >> 6;
    const int g = l >> 4;

    bf16x8 w1r[2][6], w2r[2][4];
    {
        const bf16x8* wp1 = reinterpret_cast<const bf16x8*>(wf);
        const bf16x8* wp2 = reinterpret_cast<const bf16x8*>(wf + 24576);
#pragma unroll
        for (int dm = 0; dm < 2; ++dm) {
            const int mt = 2 * w + dm;
#pragma unroll
            for (int kt = 0; kt < 6; ++kt) w1r[dm][kt] = wp1[(mt * 6 + kt) * 64 + l];
#pragma unroll
            for (int kt = 0; kt < 4; ++kt) w2r[dm][kt] = wp2[(mt * 4 + kt) * 64 + l];
        }
    }
    float4 b1v[2], b2v[2];
#pragma unroll
    for (int dm = 0; dm < 2; ++dm) {
        b1v[dm] = *reinterpret_cast<const float4*>(&b1[32 * w + 16 * dm + 4 * g]);
        b2v[dm] = *reinterpret_cast<const float4*>(&b2[32 * w + 16 * dm + 4 * g]);
    }

    const int le = t >> 2;
    const int lq = (t & 3) * 4;
    const int nt_s = le >> 4;

    for (int tile = blockIdx.x * 5; tile < blockIdx.x * 5 + 5; ++tile) {
        const int e0 = tile * 64;
        const int src = ei[e0 + le];
#pragma unroll
        for (int j = 0; j < 12; ++j) {
            const int k = lq + 16 * j;
            float4 av;
            if (j < 8) av = *reinterpret_cast<const float4*>(&x[(size_t)src * 128 + k]);
            else       av = *reinterpret_cast<const float4*>(&pe[(size_t)(e0 + le) * 64 + (k - 128)]);
            const int kt = k >> 5;
            const int lane = (le & 15) + (((k & 31) >> 3) << 4);
            const int off = ((kt * 4 + nt_s) << 10) + (lane << 4) + ((k & 4) << 1);
            *reinterpret_cast<uint2*>(Asw + off) = pack4(av.x, av.y, av.z, av.w);
        }
        int dstv[4];
#pragma unroll
        for (int nt = 0; nt < 4; ++nt) dstv[nt] = ei[NE + e0 + nt * 16 + (l & 15)];
        __syncthreads();

        f32x4 acc[2][4];
#pragma unroll
        for (int dm = 0; dm < 2; ++dm)
#pragma unroll
            for (int nt = 0; nt < 4; ++nt) acc[dm][nt] = (f32x4){0.f, 0.f, 0.f, 0.f};
#pragma unroll
        for (int kt = 0; kt < 6; ++kt) {
#pragma unroll
            for (int nt = 0; nt < 4; ++nt) {
                const bf16x8 af = *reinterpret_cast<const bf16x8*>(Asw + ((kt * 4 + nt) << 10) + (l << 4));
                acc[0][nt] = __builtin_amdgcn_mfma_f32_16x16x32_bf16(w1r[0][kt], af, acc[0][nt], 0, 0, 0);
                acc[1][nt] = __builtin_amdgcn_mfma_f32_16x16x32_bf16(w1r[1][kt], af, acc[1][nt], 0, 0, 0);
            }
        }
#pragma unroll
        for (int dm = 0; dm < 2; ++dm) {
            const float bb[4] = {b1v[dm].x, b1v[dm].y, b1v[dm].z, b1v[dm].w};
            const int lane2 = (l & 15) + ((2 * dm + (g >> 1)) << 4);
#pragma unroll
            for (int nt = 0; nt < 4; ++nt) {
                float v0 = fmaxf(acc[dm][nt][0] + bb[0], 0.f);
                float v1 = fmaxf(acc[dm][nt][1] + bb[1], 0.f);
                float v2 = fmaxf(acc[dm][nt][2] + bb[2], 0.f);
                float v3 = fmaxf(acc[dm][nt][3] + bb[3], 0.f);
                const int off = ((w * 4 + nt) << 10) + (lane2 << 4) + ((g & 1) << 3);
                *reinterpret_cast<uint2*>(Hsw + off) = pack4(v0, v1, v2, v3);
            }
        }
        __syncthreads();

        f32x4 acc2[2][4];
#pragma unroll
        for (int dm = 0; dm < 2; ++dm)
#pragma unroll
            for (int nt = 0; nt < 4; ++nt) acc2[dm][nt] = (f32x4){0.f, 0.f, 0.f, 0.f};
#pragma unroll
        for (int kt = 0; kt < 4; ++kt) {
#pragma unroll
            for (int nt = 0; nt < 4; ++nt) {
                const bf16x8 hf = *reinterpret_cast<const bf16x8*>(Hsw + ((kt * 4 + nt) << 10) + (l << 4));
                acc2[0][nt] = __builtin_amdgcn_mfma_f32_16x16x32_bf16(w2r[0][kt], hf, acc2[0][nt], 0, 0, 0);
                acc2[1][nt] = __builtin_amdgcn_mfma_f32_16x16x32_bf16(w2r[1][kt], hf, acc2[1][nt], 0, 0, 0);
            }
        }
#pragma unroll
        for (int dm = 0; dm < 2; ++dm) {
            const float bb[4] = {b2v[dm].x, b2v[dm].y, b2v[dm].z, b2v[dm].w};
            const int mbase = 32 * w + 16 * dm + 4 * g;
#pragma unroll
            for (int nt = 0; nt < 4; ++nt) {
                float* ap = &agg[(size_t)dstv[nt] * 128 + mbase];
                atomicAdd(ap + 0, acc2[dm][nt][0] + bb[0]);
                atomicAdd(ap + 1, acc2[dm][nt][1] + bb[1]);
                atomicAdd(ap + 2, acc2[dm][nt][2] + bb[2]);
                atomicAdd(ap + 3, acc2[dm][nt][3] + bb[3]);
            }
        }
    }
}

__global__ __launch_bounds__(256)
void node_legacy(const float* __restrict__ x,
                 const float* __restrict__ c1,
                 const float* __restrict__ c2,
                 const unsigned short* __restrict__ wf,
                 float* __restrict__ out)
{
    __shared__ __align__(16) unsigned char smem[32768 + 16384];
    unsigned char* Asw = smem;
    unsigned char* Hsw = smem + 32768;

    const int t = threadIdx.x;
    const int l = t & 63;
    const int w = t >> 6;
    const int g = l >> 4;

    bf16x8 u1r[2][8], u2r[2][4];
    {
        const bf16x8* up1 = reinterpret_cast<const bf16x8*>(wf + 40960);
        const bf16x8* up2 = reinterpret_cast<const bf16x8*>(wf + 73728);
#pragma unroll
        for (int dm = 0; dm < 2; ++dm) {
            const int mt = 2 * w + dm;
#pragma unroll
            for (int kt = 0; kt < 8; ++kt) u1r[dm][kt] = up1[(mt * 8 + kt) * 64 + l];
#pragma unroll
            for (int kt = 0; kt < 4; ++kt) u2r[dm][kt] = up2[(mt * 4 + kt) * 64 + l];
        }
    }
    float4 c1v[2], c2v[2];
#pragma unroll
    for (int dm = 0; dm < 2; ++dm) {
        c1v[dm] = *reinterpret_cast<const float4*>(&c1[32 * w + 16 * dm + 4 * g]);
        c2v[dm] = *reinterpret_cast<const float4*>(&c2[32 * w + 16 * dm + 4 * g]);
    }

    const int n0 = blockIdx.x * 64;
    const int le = t >> 2;
    const int lq = (t & 3) * 4;
    const int nt_s = le >> 4;
    const int node = n0 + le;
    const bool valid = node < NN;

#pragma unroll
    for (int j = 0; j < 16; ++j) {
        const int k = lq + 16 * j;
        float4 av = make_float4(0.f, 0.f, 0.f, 0.f);
        if (valid) {
            if (j < 8) av = *reinterpret_cast<const float4*>(&x[(size_t)node * 128 + k]);
            else       av = *reinterpret_cast<const float4*>(&out[(size_t)node * 128 + (k - 128)]);
        }
        const int kt = k >> 5;
        const int lane = (le & 15) + (((k & 31) >> 3) << 4);
        const int off = ((kt * 4 + nt_s) << 10) + (lane << 4) + ((k & 4) << 1);
        *reinterpret_cast<uint2*>(Asw + off) = pack4(av.x, av.y, av.z, av.w);
    }
    __syncthreads();

    f32x4 acc[2][4];
#pragma unroll
    for (int dm = 0; dm < 2; ++dm)
#pragma unroll
        for (int nt = 0; nt < 4; ++nt) acc[dm][nt] = (f32x4){0.f, 0.f, 0.f, 0.f};
#pragma unroll
    for (int kt = 0; kt < 8; ++kt) {
        bf16x8 af[4];
#pragma unroll
        for (int nt = 0; nt < 4; ++nt)
            af[nt] = *reinterpret_cast<const bf16x8*>(Asw + ((kt * 4 + nt) << 10) + (l << 4));
#pragma unroll
        for (int nt = 0; nt < 4; ++nt) {
            acc[0][nt] = __builtin_amdgcn_mfma_f32_16x16x32_bf16(u1r[0][kt], af[nt], acc[0][nt], 0, 0, 0);
            acc[1][nt] = __builtin_amdgcn_mfma_f32_16x16x32_bf16(u1r[1][kt], af[nt], acc[1][nt], 0, 0, 0);
        }
    }

#pragma unroll
    for (int dm = 0; dm < 2; ++dm) {
        const float bb[4] = {c1v[dm].x, c1v[dm].y, c1v[dm].z, c1v[dm].w};
        const int lane2 = (l & 15) + ((2 * dm + (g >> 1)) << 4);
#pragma unroll
        for (int nt = 0; nt < 4; ++nt) {
            float v0 = fmaxf(acc[dm][nt][0] + bb[0], 0.f);
            float v1 = fmaxf(acc[dm][nt][1] + bb[1], 0.f);
            float v2 = fmaxf(acc[dm][nt][2] + bb[2], 0.f);
            float v3 = fmaxf(acc[dm][nt][3] + bb[3], 0.f);
            const int off = ((w * 4 + nt) << 10) + (lane2 << 4) + ((g & 1) << 3);
            *reinterpret_cast<uint2*>(Hsw + off) = pack4(v0, v1, v2, v3);
        }
    }
    __syncthreads();

    f32x4 acc2[2][4];
#pragma unroll
    for (int dm = 0; dm < 2; ++dm)
#pragma unroll
        for (int nt = 0; nt < 4; ++nt) acc2[dm][nt] = (f32x4){0.f, 0.f, 0.f, 0.f};
#pragma unroll
    for (int kt = 0; kt < 4; ++kt) {
        bf16x8 hf[4];
#pragma unroll
        for (int nt = 0; nt < 4; ++nt)
            hf[nt] = *reinterpret_cast<const bf16x8*>(Hsw + ((kt * 4 + nt) << 10) + (l << 4));
#pragma unroll
        for (int nt = 0; nt < 4; ++nt) {
            acc2[0][nt] = __builtin_amdgcn_mfma_f32_16x16x32_bf16(u2r[0][kt], hf[nt], acc2[0][nt], 0, 0, 0);
            acc2[1][nt] = __builtin_amdgcn_mfma_f32_16x16x32_bf16(u2r[1][kt], hf[nt], acc2[1][nt], 0, 0, 0);
        }
    }

#pragma unroll
    for (int dm = 0; dm < 2; ++dm) {
        const int mbase = 32 * w + 16 * dm + 4 * g;
#pragma unroll
        for (int nt = 0; nt < 4; ++nt) {
            const int n = n0 + nt * 16 + (l & 15);
            if (n < NN) {
                float4 o;
                o.x = acc2[dm][nt][0] + c2v[dm].x;
                o.y = acc2[dm][nt][1] + c2v[dm].y;
                o.z = acc2[dm][nt][2] + c2v[dm].z;
                o.w = acc2[dm][nt][3] + c2v[dm].w;
                *reinterpret_cast<float4*>(&out[(size_t)n * 128 + mbase]) = o;
            }
        }
    }
}

extern "C" void kernel_launch(void* const* d_in, const int* in_sizes, int n_in,
                              void* d_out, int out_size, void* d_ws, size_t ws_size,
                              hipStream_t stream) {
    const float* x  = (const float*)d_in[0];
    const float* pe = (const float*)d_in[1];
    const float* W1 = (const float*)d_in[2];
    const float* b1 = (const float*)d_in[3];
    const float* W2 = (const float*)d_in[4];
    const float* b2 = (const float*)d_in[5];
    const float* U1 = (const float*)d_in[6];
    const float* c1 = (const float*)d_in[7];
    const float* U2 = (const float*)d_in[8];
    const float* c2 = (const float*)d_in[9];
    const int*   ei = (const int*)d_in[10];
    float* out = (float*)d_out;

    const size_t MB = 1 << 20;
    unsigned short* wf = (unsigned short*)d_ws;
    int* counts = (int*)((char*)d_ws + 1 * MB);
    int* offs   = (int*)((char*)d_ws + 1 * MB + 256 * 1024);
    int* cursor = (int*)((char*)d_ws + 1 * MB + 512 * 1024);
    int* bsums  = (int*)((char*)d_ws + 1 * MB + 768 * 1024);
    int* boffs  = (int*)((char*)d_ws + 1 * MB + 772 * 1024);
    int* csrpos = (int*)((char*)d_ws + 2 * MB);
    unsigned short* xb   = (unsigned short*)((char*)d_ws + 6 * MB);
    unsigned short* msgA = (unsigned short*)((char*)d_ws + 19 * MB);
    unsigned short* msgB = (unsigned short*)((char*)d_ws + 6 * MB);

    const size_t MSG_BYTES = (size_t)NE * 128 * 2;
    const size_t REQA = 19 * MB + MSG_BYTES;
    const size_t REQB = 6 * MB + MSG_BYTES;

    prep_weights<<<88, 256, 0, stream>>>(W1, W2, U1, U2, wf);

    if (ws_size >= REQB) {
        const bool tierA = ws_size >= REQA;
        unsigned short* msg = tierA ? msgA : msgB;

        hipMemsetAsync(counts, 0, 50176 * sizeof(int), stream);
        if (tierA) prep_x<<<3125, 256, 0, stream>>>(x, xb);
        hist_kernel<<<NE / 256, 256, 0, stream>>>(ei, counts);
        scan1_kernel<<<196, 256, 0, stream>>>(counts, offs, bsums);
        scan2_kernel<<<1, 256, 0, stream>>>(bsums, boffs);
        scan3_kernel<<<196, 256, 0, stream>>>(offs, boffs, cursor);
        fill_kernel<<<NE / 256, 256, 0, stream>>>(ei, cursor, csrpos);
        if (tierA) {
            edge_kernel2<1><<<NE / 64 / 5, 512, 0, stream>>>(x, xb, pe, b1, b2, ei, csrpos, wf, msg);
            node_fused<1><<<(NN + 63) / 64, 512, 0, stream>>>(x, xb, c1, c2, wf, offs, counts, msg, out);
        } else {
            edge_kernel2<0><<<NE / 64 / 5, 512, 0, stream>>>(x, nullptr, pe, b1, b2, ei, csrpos, wf, msg);
            node_fused<0><<<(NN + 63) / 64, 512, 0, stream>>>(x, nullptr, c1, c2, wf, offs, counts, msg, out);
        }
    } else {
        hipMemsetAsync(out, 0, (size_t)NN * 128 * sizeof(float), stream);
        edge_atomic<<<NE / 64 / 5, 256, 0, stream>>>(x, pe, b1, b2, ei, wf, out);
        node_legacy<<<(NN + 63) / 64, 256, 0, stream>>>(x, c1, c2, wf, out);
    }
}